// Round 29
// baseline (110.884 us; speedup 1.0000x reference)
//
#include <hip/hip_runtime.h>
#include <hip/hip_cooperative_groups.h>
#include <math.h>

#define EPS 1e-5f

typedef __attribute__((ext_vector_type(8))) short short8v;
typedef __attribute__((ext_vector_type(4))) float f32x4;
typedef __attribute__((ext_vector_type(16))) float f32x16;

// ---- bf16 split helpers (RNE) ----
__device__ __forceinline__ unsigned short bf16r(float x) {
    unsigned u = __float_as_uint(x);
    return (unsigned short)((u + 0x7FFFu + ((u >> 16) & 1u)) >> 16);
}
__device__ __forceinline__ float bf2f(unsigned short h) {
    return __uint_as_float(((unsigned)h) << 16);
}
__device__ __forceinline__ unsigned packhl(float x) {
    const unsigned short h = bf16r(x);
    const unsigned short l = bf16r(x - bf2f(h));
    return (unsigned)h | ((unsigned)l << 16);
}

// ---------------------------------------------------------------------------
// k_pre (486 blocks): conv3 Bpack (0..63), w2q/bias2 (64), Bedge/qTab/bias3/
// sf/cf (65), wf1->B1 (66..321), wf2->B2 (322..385), wf3->B3 (386..485).
// (R24-validated)
// ---------------------------------------------------------------------------
__global__ __launch_bounds__(256) void k_pre(
    const float* __restrict__ w3, const float* __restrict__ b3,
    const float* __restrict__ g3, const float* __restrict__ be3,
    const float* __restrict__ m3, const float* __restrict__ v3,
    const float* __restrict__ w2, const float* __restrict__ b2,
    const float* __restrict__ g2, const float* __restrict__ be2,
    const float* __restrict__ m2, const float* __restrict__ v2,
    const float* __restrict__ w_info, const float* __restrict__ b_info,
    const float* __restrict__ g_info, const float* __restrict__ be_info,
    const float* __restrict__ m_info, const float* __restrict__ v_info,
    const float* __restrict__ bf1, const float* __restrict__ gf1,
    const float* __restrict__ bef1, const float* __restrict__ mf1,
    const float* __restrict__ vf1,
    const float* __restrict__ bf2, const float* __restrict__ gf2,
    const float* __restrict__ bef2, const float* __restrict__ mf2,
    const float* __restrict__ vf2,
    const float* __restrict__ wf1, const float* __restrict__ wf2,
    const float* __restrict__ wf3,
    unsigned short* __restrict__ Bh, unsigned short* __restrict__ Bl,
    float* __restrict__ bias3,
    float4* __restrict__ w2q, float* __restrict__ bias2,
    unsigned short* __restrict__ Bedge,
    float4* __restrict__ qTab4,
    float* __restrict__ sf1, float* __restrict__ cf1,
    float* __restrict__ sf2, float* __restrict__ cf2,
    unsigned short* __restrict__ B1h, unsigned short* __restrict__ B1l,
    unsigned short* __restrict__ B2h, unsigned short* __restrict__ B2l,
    unsigned short* __restrict__ B3h, unsigned short* __restrict__ B3l)
{
    const int blk = blockIdx.x, tid = threadIdx.x;
    if (blk < 64) {
        const int t = blk * 256 + tid;
        const int kt = t >> 12;
        const int nt = (t >> 6) & 63;
        const int lane = t & 63;
        const int o  = nt * 16 + (lane & 15);
        const int kb = kt * 32 + ((lane >> 4) << 3);
        const float a3 = g3[o] * rsqrtf(v3[o] + EPS);
        #pragma unroll
        for (int j = 0; j < 8; ++j) {
            const float wv = a3 * w3[(size_t)o * 128 + kb + j];
            const unsigned short hi = bf16r(wv);
            Bh[(size_t)t * 8 + j] = hi;
            Bl[(size_t)t * 8 + j] = bf16r(wv - bf2f(hi));
        }
    } else if (blk == 64) {
        for (int idx = tid; idx < 2048; idx += 256) {
            const int o2 = idx & 127, cq = idx >> 7;
            const float a2 = g2[o2] * rsqrtf(v2[o2] + EPS);
            const float4 w = *(const float4*)(w2 + (size_t)o2 * 64 + cq * 4);
            w2q[cq * 128 + o2] = make_float4(a2 * w.x, a2 * w.y, a2 * w.z, a2 * w.w);
        }
        if (tid < 128) {
            const float a2 = g2[tid] * rsqrtf(v2[tid] + EPS);
            bias2[tid] = a2 * (b2[tid] - m2[tid]) + be2[tid];
        }
    } else if (blk == 65) {
        if (tid < 128) {
            const int nt = tid >> 6, lane = tid & 63;
            const int grp = lane >> 5;
            const int o = nt * 32 + (lane & 31);
            const float a = g_info[o] * rsqrtf(v_info[o] + EPS);
            const float c0 = a * w_info[o*6+0];
            const float c1 = a * w_info[o*6+1];
            const float c2 = a * w_info[o*6+2];
            const unsigned short ch0 = bf16r(c0), ch1 = bf16r(c1), ch2 = bf16r(c2);
            const unsigned short cl0 = bf16r(c0 - bf2f(ch0));
            const unsigned short cl1 = bf16r(c1 - bf2f(ch1));
            const unsigned short cl2 = bf16r(c2 - bf2f(ch2));
            unsigned short out[8] = {0,0,0,0,0,0,0,0};
            if (grp == 0) {
                out[0]=ch0; out[1]=ch1; out[2]=ch2;
                out[3]=cl0; out[4]=cl1; out[5]=cl2;
                out[6]=ch0; out[7]=ch1;
            } else {
                out[0]=ch2;
            }
            #pragma unroll
            for (int j = 0; j < 8; ++j)
                Bedge[(size_t)(nt*64 + lane)*8 + j] = out[j];
        }
        if (tid < 64) {
            const int o = tid;
            const float w0 = w_info[o*6+0], w1 = w_info[o*6+1], w2c = w_info[o*6+2];
            const float w3c = w_info[o*6+3], w4 = w_info[o*6+4], w5 = w_info[o*6+5];
            const float a = g_info[o] * rsqrtf(v_info[o] + EPS);
            qTab4[o] = make_float4(a*(w3c-w0), a*(w4-w1), a*(w5-w2c),
                                   a*(b_info[o]-m_info[o]) + be_info[o]);
        }
        for (int c = tid; c < 1024; c += 256) {
            const float a3 = g3[c] * rsqrtf(v3[c] + EPS);
            bias3[c] = a3 * (b3[c] - m3[c]) + be3[c];
        }
        for (int c = tid; c < 512; c += 256) {
            const float s = gf1[c] * rsqrtf(vf1[c] + EPS);
            sf1[c] = s;
            cf1[c] = s * (bf1[c] - mf1[c]) + bef1[c];
        }
        {
            const int c = tid;
            const float s = gf2[c] * rsqrtf(vf2[c] + EPS);
            sf2[c] = s;
            cf2[c] = s * (bf2[c] - mf2[c]) + bef2[c];
        }
    } else if (blk < 322) {
        const int idx = (blk - 66) * 256 + tid;
        const int lane = idx & 63;
        const int nt = (idx >> 6) & 15;
        const int kt = idx >> 10;
        const int n  = nt * 32 + (lane & 31);
        const int kb = kt * 16 + ((lane >> 5) << 3);
        #pragma unroll
        for (int j = 0; j < 8; ++j) {
            const float wv = wf1[(size_t)n * 1024 + kb + j];
            const unsigned short hi = bf16r(wv);
            B1h[(size_t)idx * 8 + j] = hi;
            B1l[(size_t)idx * 8 + j] = bf16r(wv - bf2f(hi));
        }
    } else if (blk < 386) {
        const int idx = (blk - 322) * 256 + tid;
        const int lane = idx & 63;
        const int nt = (idx >> 6) & 7;
        const int kt = idx >> 9;
        const int n  = nt * 32 + (lane & 31);
        const int kb = kt * 16 + ((lane >> 5) << 3);
        #pragma unroll
        for (int j = 0; j < 8; ++j) {
            const float wv = wf2[(size_t)n * 512 + kb + j];
            const unsigned short hi = bf16r(wv);
            B2h[(size_t)idx * 8 + j] = hi;
            B2l[(size_t)idx * 8 + j] = bf16r(wv - bf2f(hi));
        }
    } else {
        const int idx = (blk - 386) * 256 + tid;       // < 25600
        const int lane = idx & 63;
        const int g6 = idx >> 6;
        const int nt = g6 % 25;
        const int kt = g6 / 25;
        const int n  = nt * 32 + (lane & 31);          // < 800
        const int kb = kt * 16 + ((lane >> 5) << 3);
        #pragma unroll
        for (int j = 0; j < 8; ++j) {
            const float wv = wf3[(size_t)n * 256 + kb + j];
            const unsigned short hi = bf16r(wv);
            B3h[(size_t)idx * 8 + j] = hi;
            B3l[(size_t)idx * 8 + j] = bf16r(wv - bf2f(hi));
        }
    }
}

// ---------------------------------------------------------------------------
// k_edgeS3: fused edge-conv + max + conv2 + conv3 + global max.
// (R28-validated exact form: 960 thr = 15 waves, one n per wave.)
// ---------------------------------------------------------------------------
__global__ __launch_bounds__(960) void k_edgeS3(
    const float* __restrict__ pts,
    const float* __restrict__ info,
    const unsigned short* __restrict__ Bedge,
    const float4* __restrict__ qTab4,
    const float4* __restrict__ w2q,
    const float* __restrict__ bias2,
    const unsigned short* __restrict__ Bh,
    const unsigned short* __restrict__ Bl,
    const float* __restrict__ bias3,
    unsigned short* __restrict__ ghi,     // [256][1024] bf16 hi
    unsigned short* __restrict__ glo)     // [256][1024] bf16 lo
{
    __shared__ unsigned dsb[23400];
    __shared__ float h1s[960];
    __shared__ unsigned short h2hL[2048];
    __shared__ unsigned short h2lL[2048];

    const int tid = threadIdx.x;
    const int b = blockIdx.x;

    {
        const float4* src = (const float4*)(info + (size_t)b * 23400);
        uint4* dst = (uint4*)dsb;
        for (int i = tid; i < 5850; i += 960) {
            const float4 v = src[i];
            uint4 pv;
            pv.x = packhl(v.x); pv.y = packhl(v.y);
            pv.z = packhl(v.z); pv.w = packhl(v.w);
            dst[i] = pv;
        }
    }
    __syncthreads();

    const int wave = tid >> 6, lane = tid & 63;   // wave: 0..14
    const int la = lane & 31;
    const bool hiHalf = lane >= 32;

    {   // ---- edge-conv phase (depth-2 LDS prefetch; one n per wave) ----
        short8v bfrag0 = *(const short8v*)(Bedge + (size_t)(0*64 + lane)*8);
        short8v bfrag1 = *(const short8v*)(Bedge + (size_t)(1*64 + lane)*8);

        const f32x16 zero16 = {0.f,0.f,0.f,0.f,0.f,0.f,0.f,0.f,
                               0.f,0.f,0.f,0.f,0.f,0.f,0.f,0.f};

        {
            const int n = wave;
            float m0 = -INFINITY, m1 = -INFINITY;
            const unsigned* pb = dsb + n*3;

            unsigned w0 = 0, w1 = 0, w2 = 0;
            {
                const unsigned* p = pb + la*45;
                if (!hiHalf) { w0 = p[0]; w1 = p[1]; }
                w2 = p[2];
            }

            #pragma unroll 1
            for (int mt = 0; mt < 17; ++mt) {
                unsigned nw0 = 0, nw1 = 0, nw2 = 0;
                if (mt < 16) {
                    int nrow = (mt+1)*32 + la;
                    nrow = nrow > 519 ? 519 : nrow;
                    const unsigned* p = pb + nrow*45;
                    if (!hiHalf) { nw0 = p[0]; nw1 = p[1]; }
                    nw2 = p[2];
                }
                int4 ai;
                if (!hiHalf) {
                    ai.x = (int)((w0 & 0xFFFFu) | (w1 << 16));
                    ai.y = (int)((w2 & 0xFFFFu) | (w0 << 16));
                    ai.z = (int)((w1 & 0xFFFFu) | (w2 << 16));
                    ai.w = (int)((w0 >> 16) | (w1 & 0xFFFF0000u));
                } else {
                    ai.x = (int)(w2 >> 16);
                    ai.y = 0; ai.z = 0; ai.w = 0;
                }
                const short8v afrag = *(short8v*)&ai;
                const f32x16 r0 = __builtin_amdgcn_mfma_f32_32x32x16_bf16(afrag, bfrag0, zero16, 0,0,0);
                const f32x16 r1 = __builtin_amdgcn_mfma_f32_32x32x16_bf16(afrag, bfrag1, zero16, 0,0,0);
                #pragma unroll
                for (int c = 0; c < 16; c += 4) {
                    m0 = fmaxf(m0, fmaxf(fmaxf(r0[c], r0[c+1]),
                                         fmaxf(r0[c+2], r0[c+3])));
                    m1 = fmaxf(m1, fmaxf(fmaxf(r1[c], r1[c+1]),
                                         fmaxf(r1[c+2], r1[c+3])));
                }
                w0 = nw0; w1 = nw1; w2 = nw2;
            }
            m0 = fmaxf(m0, __shfl_xor(m0, 32));
            m1 = fmaxf(m1, __shfl_xor(m1, 32));

            if (lane < 32) {
                const float x0 = pts[b*45 + n*3 + 0];
                const float x1 = pts[b*45 + n*3 + 1];
                const float x2 = pts[b*45 + n*3 + 2];
                {
                    const int o = lane;
                    const float4 qv = qTab4[o];
                    const float bias = fmaf(qv.x, x0, fmaf(qv.y, x1, fmaf(qv.z, x2, qv.w)));
                    h1s[n*64 + o] = fmaxf(m0 + bias, 0.f);
                }
                {
                    const int o = 32 + lane;
                    const float4 qv = qTab4[o];
                    const float bias = fmaf(qv.x, x0, fmaf(qv.y, x1, fmaf(qv.z, x2, qv.w)));
                    h1s[n*64 + o] = fmaxf(m1 + bias, 0.f);
                }
            }
        }
    }
    __syncthreads();

    // ---- conv2 phase -> h2 in LDS ----
    for (int idx = tid; idx < 2048; idx += 960) {
        const int o2 = idx & 127, n = idx >> 7;
        float val = 0.f;
        if (n < 15) {
            float acc = 0.f;
            #pragma unroll
            for (int cq = 0; cq < 16; ++cq) {
                const float4 h4 = *(const float4*)(&h1s[n*64 + cq*4]);
                const float4 w4 = w2q[cq*128 + o2];
                acc = fmaf(w4.x, h4.x, fmaf(w4.y, h4.y,
                      fmaf(w4.z, h4.z, fmaf(w4.w, h4.w, acc))));
            }
            val = fmaxf(acc + bias2[o2], 0.f);
        }
        const unsigned short hi = bf16r(val);
        const unsigned short lo = bf16r(val - bf2f(hi));
        h2hL[idx] = hi;
        h2lL[idx] = lo;
    }
    __syncthreads();

    // ---- conv3 + global-max phase -> g bf16 hi/lo (nt = wave, +15) ----
    {
        const int arow = lane & 15, agrp = lane >> 4;

        short8v ahi[4], alo[4];
        {
            const unsigned short* Ab = h2hL + arow*128 + agrp*8;
            const unsigned short* Al = h2lL + arow*128 + agrp*8;
            #pragma unroll
            for (int kt = 0; kt < 4; ++kt) {
                ahi[kt] = *(const short8v*)(Ab + kt*32);
                alo[kt] = *(const short8v*)(Al + kt*32);
            }
        }

        for (int nt = wave; nt < 64; nt += 15) {
            f32x4 a0 = {0.f, 0.f, 0.f, 0.f};
            f32x4 a1 = a0, a2 = a0;
            #pragma unroll
            for (int kt = 0; kt < 4; ++kt) {
                const size_t off = (((size_t)kt*64 + nt)*64 + lane) * 8;
                const short8v bh = *(const short8v*)(Bh + off);
                const short8v bl = *(const short8v*)(Bl + off);
                a0 = __builtin_amdgcn_mfma_f32_16x16x32_bf16(ahi[kt], bh, a0, 0, 0, 0);
                a1 = __builtin_amdgcn_mfma_f32_16x16x32_bf16(ahi[kt], bl, a1, 0, 0, 0);
                a2 = __builtin_amdgcn_mfma_f32_16x16x32_bf16(alo[kt], bh, a2, 0, 0, 0);
            }
            const float r0 = a0[0] + a1[0] + a2[0];
            const float r1 = a0[1] + a1[1] + a2[1];
            const float r2 = a0[2] + a1[2] + a2[2];
            const float r3 = a0[3] + a1[3] + a2[3];
            float m = fmaxf(fmaxf(r0, r1), r2);
            if (agrp != 3) m = fmaxf(m, r3);
            m = fmaxf(m, __shfl_xor(m, 16));
            m = fmaxf(m, __shfl_xor(m, 32));
            if (lane < 16) {
                const float val = m + bias3[nt*16 + lane];
                const unsigned short hi = bf16r(val);
                ghi[(size_t)b*1024 + nt*16 + lane] = hi;
                glo[(size_t)b*1024 + nt*16 + lane] = bf16r(val - bf2f(hi));
            }
        }
    }
}

// ---------------------------------------------------------------------------
// k_fcAll: COOPERATIVE fusion of fc1m + fc2m + fc3m (R24-validated bodies)
// with grid.sync() between phases.  200 blocks x 256 thr (co-resident:
// 200 < 256 CUs, LDS 16.9KB, VGPR ~88).  Removes 2 launches + 2 gaps.
// Phase 1: blocks 0..127 = fc1 tiles.  Phase 2: blocks 0..63 = fc2 tiles.
// Phase 3: all 200 = fc3 tiles.
// ---------------------------------------------------------------------------
__global__ __launch_bounds__(256) void k_fcAll(
    const unsigned short* __restrict__ gh,   // [256][1024]
    const unsigned short* __restrict__ gl,
    const unsigned short* __restrict__ B1h, const unsigned short* __restrict__ B1l,
    const float* __restrict__ sf1, const float* __restrict__ cf1,
    unsigned short* __restrict__ f1h, unsigned short* __restrict__ f1l,
    const unsigned short* __restrict__ B2h, const unsigned short* __restrict__ B2l,
    const float* __restrict__ sf2, const float* __restrict__ cf2,
    float* __restrict__ f2out,
    unsigned short* __restrict__ f2h, unsigned short* __restrict__ f2l,
    const unsigned short* __restrict__ B3h, const unsigned short* __restrict__ B3l,
    const float* __restrict__ bias3fc,       // bf3 [800]
    float* __restrict__ C)                   // [256][800]
{
    namespace cg = cooperative_groups;
    cg::grid_group gridg = cg::this_grid();

    __shared__ float part[4][32][33];

    const int blk = blockIdx.x;
    const int tid = threadIdx.x;
    const int wave = tid >> 6, lane = tid & 63;
    const int kgrp = (lane >> 5) << 3;
    const f32x16 z16 = {0.f,0.f,0.f,0.f,0.f,0.f,0.f,0.f,
                        0.f,0.f,0.f,0.f,0.f,0.f,0.f,0.f};

    // ---- phase 1: fc1 (blocks 0..127; tiles bm=(blk&7)*32, bn=(blk>>3)*32) ----
    if (blk < 128) {
        const int bm = (blk & 7) * 32, bny = blk >> 3;
        const int m = bm + (lane & 31);
        f32x16 acc = z16;
        for (int kt = wave*16; kt < wave*16 + 16; ++kt) {
            const int kb = kt*16 + kgrp;
            const short8v ah = *(const short8v*)(gh + (size_t)m*1024 + kb);
            const short8v al = *(const short8v*)(gl + (size_t)m*1024 + kb);
            const size_t boff = ((size_t)kt*1024 + bny*64 + lane) * 8;
            const short8v bh = *(const short8v*)(B1h + boff);
            const short8v bl = *(const short8v*)(B1l + boff);
            acc = __builtin_amdgcn_mfma_f32_32x32x16_bf16(ah, bh, acc, 0,0,0);
            acc = __builtin_amdgcn_mfma_f32_32x32x16_bf16(ah, bl, acc, 0,0,0);
            acc = __builtin_amdgcn_mfma_f32_32x32x16_bf16(al, bh, acc, 0,0,0);
        }
        {
            const int n = lane & 31, mhl = (lane >> 5) << 2;
            #pragma unroll
            for (int reg = 0; reg < 16; ++reg) {
                const int mrow = (reg & 3) + 8*(reg >> 2) + mhl;
                part[wave][mrow][n] = acc[reg];
            }
        }
        __syncthreads();
        for (int i = tid; i < 1024; i += 256) {
            const int lm = i >> 5, ln = i & 31;
            const float sum = part[0][lm][ln] + part[1][lm][ln]
                            + part[2][lm][ln] + part[3][lm][ln];
            const int ch = bny*32 + ln;
            const float val = fmaxf(fmaf(sf1[ch], sum, cf1[ch]), 0.f);
            const unsigned short hi = bf16r(val);
            f1h[(size_t)(bm + lm)*512 + ch] = hi;
            f1l[(size_t)(bm + lm)*512 + ch] = bf16r(val - bf2f(hi));
        }
    }
    gridg.sync();

    // ---- phase 2: fc2 (blocks 0..63; tiles bm=(blk&7)*32, bn=(blk>>3)*32) ----
    if (blk < 64) {
        const int bm = (blk & 7) * 32, bny = blk >> 3;
        const int m = bm + (lane & 31);
        f32x16 acc = z16;
        for (int kt = wave*8; kt < wave*8 + 8; ++kt) {
            const int kb = kt*16 + kgrp;
            const short8v ah = *(const short8v*)(f1h + (size_t)m*512 + kb);
            const short8v al = *(const short8v*)(f1l + (size_t)m*512 + kb);
            const size_t boff = ((size_t)kt*512 + bny*64 + lane) * 8;
            const short8v bh = *(const short8v*)(B2h + boff);
            const short8v bl = *(const short8v*)(B2l + boff);
            acc = __builtin_amdgcn_mfma_f32_32x32x16_bf16(ah, bh, acc, 0,0,0);
            acc = __builtin_amdgcn_mfma_f32_32x32x16_bf16(ah, bl, acc, 0,0,0);
            acc = __builtin_amdgcn_mfma_f32_32x32x16_bf16(al, bh, acc, 0,0,0);
        }
        {
            const int n = lane & 31, mhl = (lane >> 5) << 2;
            #pragma unroll
            for (int reg = 0; reg < 16; ++reg) {
                const int mrow = (reg & 3) + 8*(reg >> 2) + mhl;
                part[wave][mrow][n] = acc[reg];
            }
        }
        __syncthreads();
        for (int i = tid; i < 1024; i += 256) {
            const int lm = i >> 5, ln = i & 31;
            const float sum = part[0][lm][ln] + part[1][lm][ln]
                            + part[2][lm][ln] + part[3][lm][ln];
            const int ch = bny*32 + ln;
            const float val = fmaxf(fmaf(sf2[ch], sum, cf2[ch]), 0.f);
            const size_t o = (size_t)(bm + lm)*256 + ch;
            f2out[o] = val;
            const unsigned short hi = bf16r(val);
            f2h[o] = hi;
            f2l[o] = bf16r(val - bf2f(hi));
        }
    }
    gridg.sync();

    // ---- phase 3: fc3 (all 200 blocks; bm=(blk%8)*32, nty=blk/8 <25) ----
    {
        const int bm = (blk & 7) * 32;        // blk%8 == blk&7 (200 = 25*8)
        const int nty = blk >> 3;             // 0..24
        const int m = bm + (lane & 31);
        f32x16 acc = z16;
        for (int kt = wave*4; kt < wave*4 + 4; ++kt) {
            const int kb = kt*16 + kgrp;
            const short8v ah = *(const short8v*)(f2h + (size_t)m*256 + kb);
            const short8v al = *(const short8v*)(f2l + (size_t)m*256 + kb);
            const size_t boff = (((size_t)kt*25 + nty)*64 + lane) * 8;
            const short8v bh = *(const short8v*)(B3h + boff);
            const short8v bl = *(const short8v*)(B3l + boff);
            acc = __builtin_amdgcn_mfma_f32_32x32x16_bf16(ah, bh, acc, 0,0,0);
            acc = __builtin_amdgcn_mfma_f32_32x32x16_bf16(ah, bl, acc, 0,0,0);
            acc = __builtin_amdgcn_mfma_f32_32x32x16_bf16(al, bh, acc, 0,0,0);
        }
        __syncthreads();   // part[] reuse after phase-2 readers finished (grid.sync)
        {
            const int n = lane & 31, mhl = (lane >> 5) << 2;
            #pragma unroll
            for (int reg = 0; reg < 16; ++reg) {
                const int mrow = (reg & 3) + 8*(reg >> 2) + mhl;
                part[wave][mrow][n] = acc[reg];
            }
        }
        __syncthreads();
        for (int i = tid; i < 1024; i += 256) {
            const int lm = i >> 5, ln = i & 31;
            const float sum = part[0][lm][ln] + part[1][lm][ln]
                            + part[2][lm][ln] + part[3][lm][ln];
            const int ch = nty * 32 + ln;                 // < 800
            C[(size_t)(bm + lm)*800 + ch] = sum + bias3fc[ch];
        }
    }
}

// ---------------------------------------------------------------------------
extern "C" void kernel_launch(void* const* d_in, const int* in_sizes, int n_in,
                              void* d_out, int out_size, void* d_ws, size_t ws_size,
                              hipStream_t stream)
{
    const float* pts     = (const float*)d_in[0];
    const float* info    = (const float*)d_in[2];
    const float* w_info  = (const float*)d_in[3];
    const float* b_info  = (const float*)d_in[4];
    const float* g_info  = (const float*)d_in[5];
    const float* be_info = (const float*)d_in[6];
    const float* m_info  = (const float*)d_in[7];
    const float* v_info  = (const float*)d_in[8];
    const float* w2      = (const float*)d_in[9];
    const float* b2      = (const float*)d_in[10];
    const float* g2      = (const float*)d_in[11];
    const float* be2     = (const float*)d_in[12];
    const float* m2      = (const float*)d_in[13];
    const float* v2      = (const float*)d_in[14];
    const float* w3      = (const float*)d_in[15];
    const float* b3      = (const float*)d_in[16];
    const float* g3      = (const float*)d_in[17];
    const float* be3     = (const float*)d_in[18];
    const float* m3      = (const float*)d_in[19];
    const float* v3      = (const float*)d_in[20];
    const float* wf1     = (const float*)d_in[21];
    const float* bf1     = (const float*)d_in[22];
    const float* gf1     = (const float*)d_in[23];
    const float* bef1    = (const float*)d_in[24];
    const float* mf1     = (const float*)d_in[25];
    const float* vf1     = (const float*)d_in[26];
    const float* wf2     = (const float*)d_in[27];
    const float* bf2     = (const float*)d_in[28];
    const float* gf2     = (const float*)d_in[29];
    const float* bef2    = (const float*)d_in[30];
    const float* mf2     = (const float*)d_in[31];
    const float* vf2     = (const float*)d_in[32];
    const float* wf3     = (const float*)d_in[33];
    const float* bf3     = (const float*)d_in[34];

    float* ws = (float*)d_ws;
    // fc-MFMA region (float-slots = shorts/2):  (R23-validated layout)
    unsigned short* ghi   = (unsigned short*)(ws + 0);
    unsigned short* glo   = (unsigned short*)(ws + 131072);
    unsigned short* f2h   = (unsigned short*)(ws + 0);        // reuse dead ghi
    unsigned short* f2l   = (unsigned short*)(ws + 32768);
    unsigned short* f1h   = (unsigned short*)(ws + 262144);
    unsigned short* f1l   = (unsigned short*)(ws + 327680);
    unsigned short* B1h   = (unsigned short*)(ws + 393216);
    unsigned short* B1l   = (unsigned short*)(ws + 655360);
    unsigned short* B2h   = (unsigned short*)(ws + 917504);
    unsigned short* B2l   = (unsigned short*)(ws + 983040);
    unsigned short* B3h   = (unsigned short*)(ws + 1048576);
    unsigned short* B3l   = (unsigned short*)(ws + 1150976);
    // constants region (unchanged offsets):
    unsigned short* Bh    = (unsigned short*)(ws + 1277952);
    unsigned short* Bl    = (unsigned short*)(ws + 1343488);
    float*          bias3 = ws + 1409024;
    float4*         w2q   = (float4*)(ws + 1410048);
    float*          bias2 = ws + 1418240;
    float4*         qTab4 = (float4*)(ws + 1418624);
    float*          sf1   = ws + 1418880;
    float*          cf1   = ws + 1419392;
    float*          sf2   = ws + 1419904;
    float*          cf2   = ws + 1420160;
    unsigned short* Bedge = (unsigned short*)(ws + 1420416);

    float* ret = (float*)d_out;            // [256, 800]
    float* f2  = ret + 256 * 800;          // [256, 256]

    k_pre<<<486, 256, 0, stream>>>(
        w3, b3, g3, be3, m3, v3,
        w2, b2, g2, be2, m2, v2,
        w_info, b_info, g_info, be_info, m_info, v_info,
        bf1, gf1, bef1, mf1, vf1,
        bf2, gf2, bef2, mf2, vf2,
        wf1, wf2, wf3,
        Bh, Bl, bias3, w2q, bias2, Bedge, qTab4, sf1, cf1, sf2, cf2,
        B1h, B1l, B2h, B2l, B3h, B3l);

    k_edgeS3<<<256, 960, 0, stream>>>(pts, info, Bedge, qTab4,
                                      w2q, bias2, Bh, Bl, bias3, ghi, glo);

    {
        void* args[] = {
            (void*)&ghi, (void*)&glo,
            (void*)&B1h, (void*)&B1l, (void*)&sf1, (void*)&cf1,
            (void*)&f1h, (void*)&f1l,
            (void*)&B2h, (void*)&B2l, (void*)&sf2, (void*)&cf2,
            (void*)&f2, (void*)&f2h, (void*)&f2l,
            (void*)&B3h, (void*)&B3l, (void*)&bf3, (void*)&ret
        };
        hipLaunchCooperativeKernel((void*)k_fcAll, dim3(200), dim3(256),
                                   args, 0, stream);
    }
}

// Round 30
// 55.958 us; speedup vs baseline: 1.9816x; 1.9816x over previous
//
#include <hip/hip_runtime.h>
#include <math.h>

#define EPS 1e-5f

typedef __attribute__((ext_vector_type(8))) short short8v;
typedef __attribute__((ext_vector_type(4))) float f32x4;
typedef __attribute__((ext_vector_type(16))) float f32x16;

// ---- bf16 split helpers (RNE) ----
__device__ __forceinline__ unsigned short bf16r(float x) {
    unsigned u = __float_as_uint(x);
    return (unsigned short)((u + 0x7FFFu + ((u >> 16) & 1u)) >> 16);
}
__device__ __forceinline__ float bf2f(unsigned short h) {
    return __uint_as_float(((unsigned)h) << 16);
}
__device__ __forceinline__ unsigned packhl(float x) {
    const unsigned short h = bf16r(x);
    const unsigned short l = bf16r(x - bf2f(h));
    return (unsigned)h | ((unsigned)l << 16);
}

// ---------------------------------------------------------------------------
// k_pre (486 blocks): conv3 Bpack (0..63), w2q/bias2 (64), Bedge/qTab/bias3/
// sf/cf (65), wf1->B1 (66..321), wf2->B2 (322..385), wf3->B3 (386..485).
// (R24-validated)
// ---------------------------------------------------------------------------
__global__ __launch_bounds__(256) void k_pre(
    const float* __restrict__ w3, const float* __restrict__ b3,
    const float* __restrict__ g3, const float* __restrict__ be3,
    const float* __restrict__ m3, const float* __restrict__ v3,
    const float* __restrict__ w2, const float* __restrict__ b2,
    const float* __restrict__ g2, const float* __restrict__ be2,
    const float* __restrict__ m2, const float* __restrict__ v2,
    const float* __restrict__ w_info, const float* __restrict__ b_info,
    const float* __restrict__ g_info, const float* __restrict__ be_info,
    const float* __restrict__ m_info, const float* __restrict__ v_info,
    const float* __restrict__ bf1, const float* __restrict__ gf1,
    const float* __restrict__ bef1, const float* __restrict__ mf1,
    const float* __restrict__ vf1,
    const float* __restrict__ bf2, const float* __restrict__ gf2,
    const float* __restrict__ bef2, const float* __restrict__ mf2,
    const float* __restrict__ vf2,
    const float* __restrict__ wf1, const float* __restrict__ wf2,
    const float* __restrict__ wf3,
    unsigned short* __restrict__ Bh, unsigned short* __restrict__ Bl,
    float* __restrict__ bias3,
    float4* __restrict__ w2q, float* __restrict__ bias2,
    unsigned short* __restrict__ Bedge,
    float4* __restrict__ qTab4,
    float* __restrict__ sf1, float* __restrict__ cf1,
    float* __restrict__ sf2, float* __restrict__ cf2,
    unsigned short* __restrict__ B1h, unsigned short* __restrict__ B1l,
    unsigned short* __restrict__ B2h, unsigned short* __restrict__ B2l,
    unsigned short* __restrict__ B3h, unsigned short* __restrict__ B3l)
{
    const int blk = blockIdx.x, tid = threadIdx.x;
    if (blk < 64) {
        const int t = blk * 256 + tid;
        const int kt = t >> 12;
        const int nt = (t >> 6) & 63;
        const int lane = t & 63;
        const int o  = nt * 16 + (lane & 15);
        const int kb = kt * 32 + ((lane >> 4) << 3);
        const float a3 = g3[o] * rsqrtf(v3[o] + EPS);
        #pragma unroll
        for (int j = 0; j < 8; ++j) {
            const float wv = a3 * w3[(size_t)o * 128 + kb + j];
            const unsigned short hi = bf16r(wv);
            Bh[(size_t)t * 8 + j] = hi;
            Bl[(size_t)t * 8 + j] = bf16r(wv - bf2f(hi));
        }
    } else if (blk == 64) {
        for (int idx = tid; idx < 2048; idx += 256) {
            const int o2 = idx & 127, cq = idx >> 7;
            const float a2 = g2[o2] * rsqrtf(v2[o2] + EPS);
            const float4 w = *(const float4*)(w2 + (size_t)o2 * 64 + cq * 4);
            w2q[cq * 128 + o2] = make_float4(a2 * w.x, a2 * w.y, a2 * w.z, a2 * w.w);
        }
        if (tid < 128) {
            const float a2 = g2[tid] * rsqrtf(v2[tid] + EPS);
            bias2[tid] = a2 * (b2[tid] - m2[tid]) + be2[tid];
        }
    } else if (blk == 65) {
        if (tid < 128) {
            const int nt = tid >> 6, lane = tid & 63;
            const int grp = lane >> 5;
            const int o = nt * 32 + (lane & 31);
            const float a = g_info[o] * rsqrtf(v_info[o] + EPS);
            const float c0 = a * w_info[o*6+0];
            const float c1 = a * w_info[o*6+1];
            const float c2 = a * w_info[o*6+2];
            const unsigned short ch0 = bf16r(c0), ch1 = bf16r(c1), ch2 = bf16r(c2);
            const unsigned short cl0 = bf16r(c0 - bf2f(ch0));
            const unsigned short cl1 = bf16r(c1 - bf2f(ch1));
            const unsigned short cl2 = bf16r(c2 - bf2f(ch2));
            unsigned short out[8] = {0,0,0,0,0,0,0,0};
            if (grp == 0) {
                out[0]=ch0; out[1]=ch1; out[2]=ch2;
                out[3]=cl0; out[4]=cl1; out[5]=cl2;
                out[6]=ch0; out[7]=ch1;
            } else {
                out[0]=ch2;
            }
            #pragma unroll
            for (int j = 0; j < 8; ++j)
                Bedge[(size_t)(nt*64 + lane)*8 + j] = out[j];
        }
        if (tid < 64) {
            const int o = tid;
            const float w0 = w_info[o*6+0], w1 = w_info[o*6+1], w2c = w_info[o*6+2];
            const float w3c = w_info[o*6+3], w4 = w_info[o*6+4], w5 = w_info[o*6+5];
            const float a = g_info[o] * rsqrtf(v_info[o] + EPS);
            qTab4[o] = make_float4(a*(w3c-w0), a*(w4-w1), a*(w5-w2c),
                                   a*(b_info[o]-m_info[o]) + be_info[o]);
        }
        for (int c = tid; c < 1024; c += 256) {
            const float a3 = g3[c] * rsqrtf(v3[c] + EPS);
            bias3[c] = a3 * (b3[c] - m3[c]) + be3[c];
        }
        for (int c = tid; c < 512; c += 256) {
            const float s = gf1[c] * rsqrtf(vf1[c] + EPS);
            sf1[c] = s;
            cf1[c] = s * (bf1[c] - mf1[c]) + bef1[c];
        }
        {
            const int c = tid;
            const float s = gf2[c] * rsqrtf(vf2[c] + EPS);
            sf2[c] = s;
            cf2[c] = s * (bf2[c] - mf2[c]) + bef2[c];
        }
    } else if (blk < 322) {
        const int idx = (blk - 66) * 256 + tid;
        const int lane = idx & 63;
        const int nt = (idx >> 6) & 15;
        const int kt = idx >> 10;
        const int n  = nt * 32 + (lane & 31);
        const int kb = kt * 16 + ((lane >> 5) << 3);
        #pragma unroll
        for (int j = 0; j < 8; ++j) {
            const float wv = wf1[(size_t)n * 1024 + kb + j];
            const unsigned short hi = bf16r(wv);
            B1h[(size_t)idx * 8 + j] = hi;
            B1l[(size_t)idx * 8 + j] = bf16r(wv - bf2f(hi));
        }
    } else if (blk < 386) {
        const int idx = (blk - 322) * 256 + tid;
        const int lane = idx & 63;
        const int nt = (idx >> 6) & 7;
        const int kt = idx >> 9;
        const int n  = nt * 32 + (lane & 31);
        const int kb = kt * 16 + ((lane >> 5) << 3);
        #pragma unroll
        for (int j = 0; j < 8; ++j) {
            const float wv = wf2[(size_t)n * 512 + kb + j];
            const unsigned short hi = bf16r(wv);
            B2h[(size_t)idx * 8 + j] = hi;
            B2l[(size_t)idx * 8 + j] = bf16r(wv - bf2f(hi));
        }
    } else {
        const int idx = (blk - 386) * 256 + tid;       // < 25600
        const int lane = idx & 63;
        const int g6 = idx >> 6;
        const int nt = g6 % 25;
        const int kt = g6 / 25;
        const int n  = nt * 32 + (lane & 31);          // < 800
        const int kb = kt * 16 + ((lane >> 5) << 3);
        #pragma unroll
        for (int j = 0; j < 8; ++j) {
            const float wv = wf3[(size_t)n * 256 + kb + j];
            const unsigned short hi = bf16r(wv);
            B3h[(size_t)idx * 8 + j] = hi;
            B3l[(size_t)idx * 8 + j] = bf16r(wv - bf2f(hi));
        }
    }
}

// ---------------------------------------------------------------------------
// k_edgeS3: fused edge-conv + max + conv2 + conv3 + global max.
// (R28-validated exact form: 960 thr = 15 waves, one n per wave.)
// ---------------------------------------------------------------------------
__global__ __launch_bounds__(960) void k_edgeS3(
    const float* __restrict__ pts,
    const float* __restrict__ info,
    const unsigned short* __restrict__ Bedge,
    const float4* __restrict__ qTab4,
    const float4* __restrict__ w2q,
    const float* __restrict__ bias2,
    const unsigned short* __restrict__ Bh,
    const unsigned short* __restrict__ Bl,
    const float* __restrict__ bias3,
    unsigned short* __restrict__ ghi,     // [256][1024] bf16 hi
    unsigned short* __restrict__ glo)     // [256][1024] bf16 lo
{
    __shared__ unsigned dsb[23400];
    __shared__ float h1s[960];
    __shared__ unsigned short h2hL[2048];
    __shared__ unsigned short h2lL[2048];

    const int tid = threadIdx.x;
    const int b = blockIdx.x;

    {
        const float4* src = (const float4*)(info + (size_t)b * 23400);
        uint4* dst = (uint4*)dsb;
        for (int i = tid; i < 5850; i += 960) {
            const float4 v = src[i];
            uint4 pv;
            pv.x = packhl(v.x); pv.y = packhl(v.y);
            pv.z = packhl(v.z); pv.w = packhl(v.w);
            dst[i] = pv;
        }
    }
    __syncthreads();

    const int wave = tid >> 6, lane = tid & 63;   // wave: 0..14
    const int la = lane & 31;
    const bool hiHalf = lane >= 32;

    {   // ---- edge-conv phase (depth-2 LDS prefetch; one n per wave) ----
        short8v bfrag0 = *(const short8v*)(Bedge + (size_t)(0*64 + lane)*8);
        short8v bfrag1 = *(const short8v*)(Bedge + (size_t)(1*64 + lane)*8);

        const f32x16 zero16 = {0.f,0.f,0.f,0.f,0.f,0.f,0.f,0.f,
                               0.f,0.f,0.f,0.f,0.f,0.f,0.f,0.f};

        {
            const int n = wave;
            float m0 = -INFINITY, m1 = -INFINITY;
            const unsigned* pb = dsb + n*3;

            unsigned w0 = 0, w1 = 0, w2 = 0;
            {
                const unsigned* p = pb + la*45;
                if (!hiHalf) { w0 = p[0]; w1 = p[1]; }
                w2 = p[2];
            }

            #pragma unroll 1
            for (int mt = 0; mt < 17; ++mt) {
                unsigned nw0 = 0, nw1 = 0, nw2 = 0;
                if (mt < 16) {
                    int nrow = (mt+1)*32 + la;
                    nrow = nrow > 519 ? 519 : nrow;
                    const unsigned* p = pb + nrow*45;
                    if (!hiHalf) { nw0 = p[0]; nw1 = p[1]; }
                    nw2 = p[2];
                }
                int4 ai;
                if (!hiHalf) {
                    ai.x = (int)((w0 & 0xFFFFu) | (w1 << 16));
                    ai.y = (int)((w2 & 0xFFFFu) | (w0 << 16));
                    ai.z = (int)((w1 & 0xFFFFu) | (w2 << 16));
                    ai.w = (int)((w0 >> 16) | (w1 & 0xFFFF0000u));
                } else {
                    ai.x = (int)(w2 >> 16);
                    ai.y = 0; ai.z = 0; ai.w = 0;
                }
                const short8v afrag = *(short8v*)&ai;
                const f32x16 r0 = __builtin_amdgcn_mfma_f32_32x32x16_bf16(afrag, bfrag0, zero16, 0,0,0);
                const f32x16 r1 = __builtin_amdgcn_mfma_f32_32x32x16_bf16(afrag, bfrag1, zero16, 0,0,0);
                #pragma unroll
                for (int c = 0; c < 16; c += 4) {
                    m0 = fmaxf(m0, fmaxf(fmaxf(r0[c], r0[c+1]),
                                         fmaxf(r0[c+2], r0[c+3])));
                    m1 = fmaxf(m1, fmaxf(fmaxf(r1[c], r1[c+1]),
                                         fmaxf(r1[c+2], r1[c+3])));
                }
                w0 = nw0; w1 = nw1; w2 = nw2;
            }
            m0 = fmaxf(m0, __shfl_xor(m0, 32));
            m1 = fmaxf(m1, __shfl_xor(m1, 32));

            if (lane < 32) {
                const float x0 = pts[b*45 + n*3 + 0];
                const float x1 = pts[b*45 + n*3 + 1];
                const float x2 = pts[b*45 + n*3 + 2];
                {
                    const int o = lane;
                    const float4 qv = qTab4[o];
                    const float bias = fmaf(qv.x, x0, fmaf(qv.y, x1, fmaf(qv.z, x2, qv.w)));
                    h1s[n*64 + o] = fmaxf(m0 + bias, 0.f);
                }
                {
                    const int o = 32 + lane;
                    const float4 qv = qTab4[o];
                    const float bias = fmaf(qv.x, x0, fmaf(qv.y, x1, fmaf(qv.z, x2, qv.w)));
                    h1s[n*64 + o] = fmaxf(m1 + bias, 0.f);
                }
            }
        }
    }
    __syncthreads();

    // ---- conv2 phase -> h2 in LDS ----
    for (int idx = tid; idx < 2048; idx += 960) {
        const int o2 = idx & 127, n = idx >> 7;
        float val = 0.f;
        if (n < 15) {
            float acc = 0.f;
            #pragma unroll
            for (int cq = 0; cq < 16; ++cq) {
                const float4 h4 = *(const float4*)(&h1s[n*64 + cq*4]);
                const float4 w4 = w2q[cq*128 + o2];
                acc = fmaf(w4.x, h4.x, fmaf(w4.y, h4.y,
                      fmaf(w4.z, h4.z, fmaf(w4.w, h4.w, acc))));
            }
            val = fmaxf(acc + bias2[o2], 0.f);
        }
        const unsigned short hi = bf16r(val);
        const unsigned short lo = bf16r(val - bf2f(hi));
        h2hL[idx] = hi;
        h2lL[idx] = lo;
    }
    __syncthreads();

    // ---- conv3 + global-max phase -> g bf16 hi/lo (nt = wave, +15) ----
    {
        const int arow = lane & 15, agrp = lane >> 4;

        short8v ahi[4], alo[4];
        {
            const unsigned short* Ab = h2hL + arow*128 + agrp*8;
            const unsigned short* Al = h2lL + arow*128 + agrp*8;
            #pragma unroll
            for (int kt = 0; kt < 4; ++kt) {
                ahi[kt] = *(const short8v*)(Ab + kt*32);
                alo[kt] = *(const short8v*)(Al + kt*32);
            }
        }

        for (int nt = wave; nt < 64; nt += 15) {
            f32x4 a0 = {0.f, 0.f, 0.f, 0.f};
            f32x4 a1 = a0, a2 = a0;
            #pragma unroll
            for (int kt = 0; kt < 4; ++kt) {
                const size_t off = (((size_t)kt*64 + nt)*64 + lane) * 8;
                const short8v bh = *(const short8v*)(Bh + off);
                const short8v bl = *(const short8v*)(Bl + off);
                a0 = __builtin_amdgcn_mfma_f32_16x16x32_bf16(ahi[kt], bh, a0, 0, 0, 0);
                a1 = __builtin_amdgcn_mfma_f32_16x16x32_bf16(ahi[kt], bl, a1, 0, 0, 0);
                a2 = __builtin_amdgcn_mfma_f32_16x16x32_bf16(alo[kt], bh, a2, 0, 0, 0);
            }
            const float r0 = a0[0] + a1[0] + a2[0];
            const float r1 = a0[1] + a1[1] + a2[1];
            const float r2 = a0[2] + a1[2] + a2[2];
            const float r3 = a0[3] + a1[3] + a2[3];
            float m = fmaxf(fmaxf(r0, r1), r2);
            if (agrp != 3) m = fmaxf(m, r3);
            m = fmaxf(m, __shfl_xor(m, 16));
            m = fmaxf(m, __shfl_xor(m, 32));
            if (lane < 16) {
                const float val = m + bias3[nt*16 + lane];
                const unsigned short hi = bf16r(val);
                ghi[(size_t)b*1024 + nt*16 + lane] = hi;
                glo[(size_t)b*1024 + nt*16 + lane] = bf16r(val - bf2f(hi));
            }
        }
    }
}

// ---------------------------------------------------------------------------
// k_fc1m: fc1 via bf16x3 MFMA.  (R24-validated exact form)
// ---------------------------------------------------------------------------
__global__ __launch_bounds__(256) void k_fc1m(
    const unsigned short* __restrict__ gh,   // [256][1024]
    const unsigned short* __restrict__ gl,
    const unsigned short* __restrict__ B1h,  // [64][16][64][8]
    const unsigned short* __restrict__ B1l,
    const float* __restrict__ sf1, const float* __restrict__ cf1,
    unsigned short* __restrict__ f1h,        // [256][512]
    unsigned short* __restrict__ f1l)
{
    __shared__ float part[4][32][33];

    const int tid = threadIdx.x;
    const int bm = blockIdx.x * 32, bn = blockIdx.y * 32;
    const int wave = tid >> 6, lane = tid & 63;
    const int m = bm + (lane & 31);
    const int kgrp = (lane >> 5) << 3;

    f32x16 acc = {0.f,0.f,0.f,0.f,0.f,0.f,0.f,0.f,
                  0.f,0.f,0.f,0.f,0.f,0.f,0.f,0.f};

    for (int kt = wave*16; kt < wave*16 + 16; ++kt) {
        const int kb = kt*16 + kgrp;
        const short8v ah = *(const short8v*)(gh + (size_t)m*1024 + kb);
        const short8v al = *(const short8v*)(gl + (size_t)m*1024 + kb);
        const size_t boff = ((size_t)kt*1024 + blockIdx.y*64 + lane) * 8;
        const short8v bh = *(const short8v*)(B1h + boff);
        const short8v bl = *(const short8v*)(B1l + boff);
        acc = __builtin_amdgcn_mfma_f32_32x32x16_bf16(ah, bh, acc, 0,0,0);
        acc = __builtin_amdgcn_mfma_f32_32x32x16_bf16(ah, bl, acc, 0,0,0);
        acc = __builtin_amdgcn_mfma_f32_32x32x16_bf16(al, bh, acc, 0,0,0);
    }
    {
        const int n = lane & 31, mhl = (lane >> 5) << 2;
        #pragma unroll
        for (int reg = 0; reg < 16; ++reg) {
            const int mrow = (reg & 3) + 8*(reg >> 2) + mhl;
            part[wave][mrow][n] = acc[reg];
        }
    }
    __syncthreads();

    for (int i = tid; i < 1024; i += 256) {
        const int lm = i >> 5, ln = i & 31;
        const float sum = part[0][lm][ln] + part[1][lm][ln]
                        + part[2][lm][ln] + part[3][lm][ln];
        const int ch = bn + ln;
        const float val = fmaxf(fmaf(sf1[ch], sum, cf1[ch]), 0.f);
        const unsigned short hi = bf16r(val);
        f1h[(size_t)(bm + lm)*512 + ch] = hi;
        f1l[(size_t)(bm + lm)*512 + ch] = bf16r(val - bf2f(hi));
    }
}

// ---------------------------------------------------------------------------
// k_fc2m: fc2 via bf16x3 MFMA; emits f2 fp32 (d_out) + bf16 hi/lo (ws).
// (R24-validated exact form)
// ---------------------------------------------------------------------------
__global__ __launch_bounds__(256) void k_fc2m(
    const unsigned short* __restrict__ f1h,  // [256][512]
    const unsigned short* __restrict__ f1l,
    const unsigned short* __restrict__ B2h,  // [32][8][64][8]
    const unsigned short* __restrict__ B2l,
    const float* __restrict__ sf2, const float* __restrict__ cf2,
    float* __restrict__ f2out,               // [256][256] fp32 (d_out tail)
    unsigned short* __restrict__ f2h,        // [256][256] bf16 hi
    unsigned short* __restrict__ f2l)        // [256][256] bf16 lo
{
    __shared__ float part[4][32][33];

    const int tid = threadIdx.x;
    const int bm = blockIdx.x * 32, bn = blockIdx.y * 32;
    const int wave = tid >> 6, lane = tid & 63;
    const int m = bm + (lane & 31);
    const int kgrp = (lane >> 5) << 3;

    f32x16 acc = {0.f,0.f,0.f,0.f,0.f,0.f,0.f,0.f,
                  0.f,0.f,0.f,0.f,0.f,0.f,0.f,0.f};

    for (int kt = wave*8; kt < wave*8 + 8; ++kt) {
        const int kb = kt*16 + kgrp;
        const short8v ah = *(const short8v*)(f1h + (size_t)m*512 + kb);
        const short8v al = *(const short8v*)(f1l + (size_t)m*512 + kb);
        const size_t boff = ((size_t)kt*512 + blockIdx.y*64 + lane) * 8;
        const short8v bh = *(const short8v*)(B2h + boff);
        const short8v bl = *(const short8v*)(B2l + boff);
        acc = __builtin_amdgcn_mfma_f32_32x32x16_bf16(ah, bh, acc, 0,0,0);
        acc = __builtin_amdgcn_mfma_f32_32x32x16_bf16(ah, bl, acc, 0,0,0);
        acc = __builtin_amdgcn_mfma_f32_32x32x16_bf16(al, bh, acc, 0,0,0);
    }
    {
        const int n = lane & 31, mhl = (lane >> 5) << 2;
        #pragma unroll
        for (int reg = 0; reg < 16; ++reg) {
            const int mrow = (reg & 3) + 8*(reg >> 2) + mhl;
            part[wave][mrow][n] = acc[reg];
        }
    }
    __syncthreads();

    for (int i = tid; i < 1024; i += 256) {
        const int lm = i >> 5, ln = i & 31;
        const float sum = part[0][lm][ln] + part[1][lm][ln]
                        + part[2][lm][ln] + part[3][lm][ln];
        const int ch = bn + ln;
        const float val = fmaxf(fmaf(sf2[ch], sum, cf2[ch]), 0.f);
        const size_t o = (size_t)(bm + lm)*256 + ch;
        f2out[o] = val;
        const unsigned short hi = bf16r(val);
        f2h[o] = hi;
        f2l[o] = bf16r(val - bf2f(hi));
    }
}

// ---------------------------------------------------------------------------
// k_fc3m: fc3 via bf16x3 MFMA.  (R24-validated exact form)
// ---------------------------------------------------------------------------
__global__ __launch_bounds__(256) void k_fc3m(
    const unsigned short* __restrict__ f2h,  // [256][256]
    const unsigned short* __restrict__ f2l,
    const unsigned short* __restrict__ B3h,  // [16][25][64][8]
    const unsigned short* __restrict__ B3l,
    const float* __restrict__ bias,          // bf3 [800]
    float* __restrict__ C)                   // [256][800]
{
    __shared__ float part[4][32][33];

    const int tid = threadIdx.x;
    const int bm = blockIdx.x * 32;
    const int wave = tid >> 6, lane = tid & 63;
    const int m = bm + (lane & 31);
    const int kgrp = (lane >> 5) << 3;

    f32x16 acc = {0.f,0.f,0.f,0.f,0.f,0.f,0.f,0.f,
                  0.f,0.f,0.f,0.f,0.f,0.f,0.f,0.f};

    for (int kt = wave*4; kt < wave*4 + 4; ++kt) {
        const int kb = kt*16 + kgrp;
        const short8v ah = *(const short8v*)(f2h + (size_t)m*256 + kb);
        const short8v al = *(const short8v*)(f2l + (size_t)m*256 + kb);
        const size_t boff = (((size_t)kt*25 + blockIdx.y)*64 + lane) * 8;
        const short8v bh = *(const short8v*)(B3h + boff);
        const short8v bl = *(const short8v*)(B3l + boff);
        acc = __builtin_amdgcn_mfma_f32_32x32x16_bf16(ah, bh, acc, 0,0,0);
        acc = __builtin_amdgcn_mfma_f32_32x32x16_bf16(ah, bl, acc, 0,0,0);
        acc = __builtin_amdgcn_mfma_f32_32x32x16_bf16(al, bh, acc, 0,0,0);
    }
    {
        const int n = lane & 31, mhl = (lane >> 5) << 2;
        #pragma unroll
        for (int reg = 0; reg < 16; ++reg) {
            const int mrow = (reg & 3) + 8*(reg >> 2) + mhl;
            part[wave][mrow][n] = acc[reg];
        }
    }
    __syncthreads();

    for (int i = tid; i < 1024; i += 256) {
        const int lm = i >> 5, ln = i & 31;
        const float sum = part[0][lm][ln] + part[1][lm][ln]
                        + part[2][lm][ln] + part[3][lm][ln];
        const int ch = blockIdx.y * 32 + ln;             // < 800
        C[(size_t)(bm + lm)*800 + ch] = sum + bias[ch];
    }
}

// ---------------------------------------------------------------------------
extern "C" void kernel_launch(void* const* d_in, const int* in_sizes, int n_in,
                              void* d_out, int out_size, void* d_ws, size_t ws_size,
                              hipStream_t stream)
{
    const float* pts     = (const float*)d_in[0];
    const float* info    = (const float*)d_in[2];
    const float* w_info  = (const float*)d_in[3];
    const float* b_info  = (const float*)d_in[4];
    const float* g_info  = (const float*)d_in[5];
    const float* be_info = (const float*)d_in[6];
    const float* m_info  = (const float*)d_in[7];
    const float* v_info  = (const float*)d_in[8];
    const float* w2      = (const float*)d_in[9];
    const float* b2      = (const float*)d_in[10];
    const float* g2      = (const float*)d_in[11];
    const float* be2     = (const float*)d_in[12];
    const float* m2      = (const float*)d_in[13];
    const float* v2      = (const float*)d_in[14];
    const float* w3      = (const float*)d_in[15];
    const float* b3      = (const float*)d_in[16];
    const float* g3      = (const float*)d_in[17];
    const float* be3     = (const float*)d_in[18];
    const float* m3      = (const float*)d_in[19];
    const float* v3      = (const float*)d_in[20];
    const float* wf1     = (const float*)d_in[21];
    const float* bf1     = (const float*)d_in[22];
    const float* gf1     = (const float*)d_in[23];
    const float* bef1    = (const float*)d_in[24];
    const float* mf1     = (const float*)d_in[25];
    const float* vf1     = (const float*)d_in[26];
    const float* wf2     = (const float*)d_in[27];
    const float* bf2     = (const float*)d_in[28];
    const float* gf2     = (const float*)d_in[29];
    const float* bef2    = (const float*)d_in[30];
    const float* mf2     = (const float*)d_in[31];
    const float* vf2     = (const float*)d_in[32];
    const float* wf3     = (const float*)d_in[33];
    const float* bf3     = (const float*)d_in[34];

    float* ws = (float*)d_ws;
    // fc-MFMA region (float-slots = shorts/2):  (R23-validated layout)
    unsigned short* ghi   = (unsigned short*)(ws + 0);
    unsigned short* glo   = (unsigned short*)(ws + 131072);
    unsigned short* f2h   = (unsigned short*)(ws + 0);        // reuse dead ghi
    unsigned short* f2l   = (unsigned short*)(ws + 32768);
    unsigned short* f1h   = (unsigned short*)(ws + 262144);
    unsigned short* f1l   = (unsigned short*)(ws + 327680);
    unsigned short* B1h   = (unsigned short*)(ws + 393216);
    unsigned short* B1l   = (unsigned short*)(ws + 655360);
    unsigned short* B2h   = (unsigned short*)(ws + 917504);
    unsigned short* B2l   = (unsigned short*)(ws + 983040);
    unsigned short* B3h   = (unsigned short*)(ws + 1048576);
    unsigned short* B3l   = (unsigned short*)(ws + 1150976);
    // constants region (unchanged offsets):
    unsigned short* Bh    = (unsigned short*)(ws + 1277952);
    unsigned short* Bl    = (unsigned short*)(ws + 1343488);
    float*          bias3 = ws + 1409024;
    float4*         w2q   = (float4*)(ws + 1410048);
    float*          bias2 = ws + 1418240;
    float4*         qTab4 = (float4*)(ws + 1418624);
    float*          sf1   = ws + 1418880;
    float*          cf1   = ws + 1419392;
    float*          sf2   = ws + 1419904;
    float*          cf2   = ws + 1420160;
    unsigned short* Bedge = (unsigned short*)(ws + 1420416);

    float* ret = (float*)d_out;            // [256, 800]
    float* f2  = ret + 256 * 800;          // [256, 256]

    k_pre<<<486, 256, 0, stream>>>(
        w3, b3, g3, be3, m3, v3,
        w2, b2, g2, be2, m2, v2,
        w_info, b_info, g_info, be_info, m_info, v_info,
        bf1, gf1, bef1, mf1, vf1,
        bf2, gf2, bef2, mf2, vf2,
        wf1, wf2, wf3,
        Bh, Bl, bias3, w2q, bias2, Bedge, qTab4, sf1, cf1, sf2, cf2,
        B1h, B1l, B2h, B2l, B3h, B3l);

    k_edgeS3<<<256, 960, 0, stream>>>(pts, info, Bedge, qTab4,
                                      w2q, bias2, Bh, Bl, bias3, ghi, glo);

    k_fc1m<<<dim3(8, 16), 256, 0, stream>>>(ghi, glo, B1h, B1l,
                                            sf1, cf1, f1h, f1l);

    k_fc2m<<<dim3(8, 8), 256, 0, stream>>>(f1h, f1l, B2h, B2l,
                                           sf2, cf2, f2, f2h, f2l);

    k_fc3m<<<dim3(8, 25), 256, 0, stream>>>(f2h, f2l, B3h, B3l, bf3, ret);
}

// Round 31
// 54.437 us; speedup vs baseline: 2.0369x; 1.0279x over previous
//
#include <hip/hip_runtime.h>
#include <math.h>

#define EPS 1e-5f

typedef __attribute__((ext_vector_type(8))) short short8v;
typedef __attribute__((ext_vector_type(4))) float f32x4;
typedef __attribute__((ext_vector_type(16))) float f32x16;

// ---- bf16 split helpers (RNE) ----
__device__ __forceinline__ unsigned short bf16r(float x) {
    unsigned u = __float_as_uint(x);
    return (unsigned short)((u + 0x7FFFu + ((u >> 16) & 1u)) >> 16);
}
__device__ __forceinline__ float bf2f(unsigned short h) {
    return __uint_as_float(((unsigned)h) << 16);
}
__device__ __forceinline__ unsigned packhl(float x) {
    const unsigned short h = bf16r(x);
    const unsigned short l = bf16r(x - bf2f(h));
    return (unsigned)h | ((unsigned)l << 16);
}

// ---------------------------------------------------------------------------
// k_pre (486 blocks): conv3 Bpack (0..63), w2q/bias2 (64), Bedge/qTab/bias3/
// sf/cf (65), wf1->B1 (66..321), wf2->B2 (322..385), wf3->B3 (386..485).
// (R24-validated)
// ---------------------------------------------------------------------------
__global__ __launch_bounds__(256) void k_pre(
    const float* __restrict__ w3, const float* __restrict__ b3,
    const float* __restrict__ g3, const float* __restrict__ be3,
    const float* __restrict__ m3, const float* __restrict__ v3,
    const float* __restrict__ w2, const float* __restrict__ b2,
    const float* __restrict__ g2, const float* __restrict__ be2,
    const float* __restrict__ m2, const float* __restrict__ v2,
    const float* __restrict__ w_info, const float* __restrict__ b_info,
    const float* __restrict__ g_info, const float* __restrict__ be_info,
    const float* __restrict__ m_info, const float* __restrict__ v_info,
    const float* __restrict__ bf1, const float* __restrict__ gf1,
    const float* __restrict__ bef1, const float* __restrict__ mf1,
    const float* __restrict__ vf1,
    const float* __restrict__ bf2, const float* __restrict__ gf2,
    const float* __restrict__ bef2, const float* __restrict__ mf2,
    const float* __restrict__ vf2,
    const float* __restrict__ wf1, const float* __restrict__ wf2,
    const float* __restrict__ wf3,
    unsigned short* __restrict__ Bh, unsigned short* __restrict__ Bl,
    float* __restrict__ bias3,
    float4* __restrict__ w2q, float* __restrict__ bias2,
    unsigned short* __restrict__ Bedge,
    float4* __restrict__ qTab4,
    float* __restrict__ sf1, float* __restrict__ cf1,
    float* __restrict__ sf2, float* __restrict__ cf2,
    unsigned short* __restrict__ B1h, unsigned short* __restrict__ B1l,
    unsigned short* __restrict__ B2h, unsigned short* __restrict__ B2l,
    unsigned short* __restrict__ B3h, unsigned short* __restrict__ B3l)
{
    const int blk = blockIdx.x, tid = threadIdx.x;
    if (blk < 64) {
        const int t = blk * 256 + tid;
        const int kt = t >> 12;
        const int nt = (t >> 6) & 63;
        const int lane = t & 63;
        const int o  = nt * 16 + (lane & 15);
        const int kb = kt * 32 + ((lane >> 4) << 3);
        const float a3 = g3[o] * rsqrtf(v3[o] + EPS);
        #pragma unroll
        for (int j = 0; j < 8; ++j) {
            const float wv = a3 * w3[(size_t)o * 128 + kb + j];
            const unsigned short hi = bf16r(wv);
            Bh[(size_t)t * 8 + j] = hi;
            Bl[(size_t)t * 8 + j] = bf16r(wv - bf2f(hi));
        }
    } else if (blk == 64) {
        for (int idx = tid; idx < 2048; idx += 256) {
            const int o2 = idx & 127, cq = idx >> 7;
            const float a2 = g2[o2] * rsqrtf(v2[o2] + EPS);
            const float4 w = *(const float4*)(w2 + (size_t)o2 * 64 + cq * 4);
            w2q[cq * 128 + o2] = make_float4(a2 * w.x, a2 * w.y, a2 * w.z, a2 * w.w);
        }
        if (tid < 128) {
            const float a2 = g2[tid] * rsqrtf(v2[tid] + EPS);
            bias2[tid] = a2 * (b2[tid] - m2[tid]) + be2[tid];
        }
    } else if (blk == 65) {
        if (tid < 128) {
            const int nt = tid >> 6, lane = tid & 63;
            const int grp = lane >> 5;
            const int o = nt * 32 + (lane & 31);
            const float a = g_info[o] * rsqrtf(v_info[o] + EPS);
            const float c0 = a * w_info[o*6+0];
            const float c1 = a * w_info[o*6+1];
            const float c2 = a * w_info[o*6+2];
            const unsigned short ch0 = bf16r(c0), ch1 = bf16r(c1), ch2 = bf16r(c2);
            const unsigned short cl0 = bf16r(c0 - bf2f(ch0));
            const unsigned short cl1 = bf16r(c1 - bf2f(ch1));
            const unsigned short cl2 = bf16r(c2 - bf2f(ch2));
            unsigned short out[8] = {0,0,0,0,0,0,0,0};
            if (grp == 0) {
                out[0]=ch0; out[1]=ch1; out[2]=ch2;
                out[3]=cl0; out[4]=cl1; out[5]=cl2;
                out[6]=ch0; out[7]=ch1;
            } else {
                out[0]=ch2;
            }
            #pragma unroll
            for (int j = 0; j < 8; ++j)
                Bedge[(size_t)(nt*64 + lane)*8 + j] = out[j];
        }
        if (tid < 64) {
            const int o = tid;
            const float w0 = w_info[o*6+0], w1 = w_info[o*6+1], w2c = w_info[o*6+2];
            const float w3c = w_info[o*6+3], w4 = w_info[o*6+4], w5 = w_info[o*6+5];
            const float a = g_info[o] * rsqrtf(v_info[o] + EPS);
            qTab4[o] = make_float4(a*(w3c-w0), a*(w4-w1), a*(w5-w2c),
                                   a*(b_info[o]-m_info[o]) + be_info[o]);
        }
        for (int c = tid; c < 1024; c += 256) {
            const float a3 = g3[c] * rsqrtf(v3[c] + EPS);
            bias3[c] = a3 * (b3[c] - m3[c]) + be3[c];
        }
        for (int c = tid; c < 512; c += 256) {
            const float s = gf1[c] * rsqrtf(vf1[c] + EPS);
            sf1[c] = s;
            cf1[c] = s * (bf1[c] - mf1[c]) + bef1[c];
        }
        {
            const int c = tid;
            const float s = gf2[c] * rsqrtf(vf2[c] + EPS);
            sf2[c] = s;
            cf2[c] = s * (bf2[c] - mf2[c]) + bef2[c];
        }
    } else if (blk < 322) {
        const int idx = (blk - 66) * 256 + tid;
        const int lane = idx & 63;
        const int nt = (idx >> 6) & 15;
        const int kt = idx >> 10;
        const int n  = nt * 32 + (lane & 31);
        const int kb = kt * 16 + ((lane >> 5) << 3);
        #pragma unroll
        for (int j = 0; j < 8; ++j) {
            const float wv = wf1[(size_t)n * 1024 + kb + j];
            const unsigned short hi = bf16r(wv);
            B1h[(size_t)idx * 8 + j] = hi;
            B1l[(size_t)idx * 8 + j] = bf16r(wv - bf2f(hi));
        }
    } else if (blk < 386) {
        const int idx = (blk - 322) * 256 + tid;
        const int lane = idx & 63;
        const int nt = (idx >> 6) & 7;
        const int kt = idx >> 9;
        const int n  = nt * 32 + (lane & 31);
        const int kb = kt * 16 + ((lane >> 5) << 3);
        #pragma unroll
        for (int j = 0; j < 8; ++j) {
            const float wv = wf2[(size_t)n * 512 + kb + j];
            const unsigned short hi = bf16r(wv);
            B2h[(size_t)idx * 8 + j] = hi;
            B2l[(size_t)idx * 8 + j] = bf16r(wv - bf2f(hi));
        }
    } else {
        const int idx = (blk - 386) * 256 + tid;       // < 25600
        const int lane = idx & 63;
        const int g6 = idx >> 6;
        const int nt = g6 % 25;
        const int kt = g6 / 25;
        const int n  = nt * 32 + (lane & 31);          // < 800
        const int kb = kt * 16 + ((lane >> 5) << 3);
        #pragma unroll
        for (int j = 0; j < 8; ++j) {
            const float wv = wf3[(size_t)n * 256 + kb + j];
            const unsigned short hi = bf16r(wv);
            B3h[(size_t)idx * 8 + j] = hi;
            B3l[(size_t)idx * 8 + j] = bf16r(wv - bf2f(hi));
        }
    }
}

// ---------------------------------------------------------------------------
// k_edgeS3: fused edge-conv + max + conv2 + conv3 + global max.
// (R28-validated exact form: 960 thr = 15 waves, one n per wave.)
// ---------------------------------------------------------------------------
__global__ __launch_bounds__(960) void k_edgeS3(
    const float* __restrict__ pts,
    const float* __restrict__ info,
    const unsigned short* __restrict__ Bedge,
    const float4* __restrict__ qTab4,
    const float4* __restrict__ w2q,
    const float* __restrict__ bias2,
    const unsigned short* __restrict__ Bh,
    const unsigned short* __restrict__ Bl,
    const float* __restrict__ bias3,
    unsigned short* __restrict__ ghi,     // [256][1024] bf16 hi
    unsigned short* __restrict__ glo)     // [256][1024] bf16 lo
{
    __shared__ unsigned dsb[23400];
    __shared__ float h1s[960];
    __shared__ unsigned short h2hL[2048];
    __shared__ unsigned short h2lL[2048];

    const int tid = threadIdx.x;
    const int b = blockIdx.x;

    {
        const float4* src = (const float4*)(info + (size_t)b * 23400);
        uint4* dst = (uint4*)dsb;
        for (int i = tid; i < 5850; i += 960) {
            const float4 v = src[i];
            uint4 pv;
            pv.x = packhl(v.x); pv.y = packhl(v.y);
            pv.z = packhl(v.z); pv.w = packhl(v.w);
            dst[i] = pv;
        }
    }
    __syncthreads();

    const int wave = tid >> 6, lane = tid & 63;   // wave: 0..14
    const int la = lane & 31;
    const bool hiHalf = lane >= 32;

    {   // ---- edge-conv phase (depth-2 LDS prefetch; one n per wave) ----
        short8v bfrag0 = *(const short8v*)(Bedge + (size_t)(0*64 + lane)*8);
        short8v bfrag1 = *(const short8v*)(Bedge + (size_t)(1*64 + lane)*8);

        const f32x16 zero16 = {0.f,0.f,0.f,0.f,0.f,0.f,0.f,0.f,
                               0.f,0.f,0.f,0.f,0.f,0.f,0.f,0.f};

        {
            const int n = wave;
            float m0 = -INFINITY, m1 = -INFINITY;
            const unsigned* pb = dsb + n*3;

            unsigned w0 = 0, w1 = 0, w2 = 0;
            {
                const unsigned* p = pb + la*45;
                if (!hiHalf) { w0 = p[0]; w1 = p[1]; }
                w2 = p[2];
            }

            #pragma unroll 1
            for (int mt = 0; mt < 17; ++mt) {
                unsigned nw0 = 0, nw1 = 0, nw2 = 0;
                if (mt < 16) {
                    int nrow = (mt+1)*32 + la;
                    nrow = nrow > 519 ? 519 : nrow;
                    const unsigned* p = pb + nrow*45;
                    if (!hiHalf) { nw0 = p[0]; nw1 = p[1]; }
                    nw2 = p[2];
                }
                int4 ai;
                if (!hiHalf) {
                    ai.x = (int)((w0 & 0xFFFFu) | (w1 << 16));
                    ai.y = (int)((w2 & 0xFFFFu) | (w0 << 16));
                    ai.z = (int)((w1 & 0xFFFFu) | (w2 << 16));
                    ai.w = (int)((w0 >> 16) | (w1 & 0xFFFF0000u));
                } else {
                    ai.x = (int)(w2 >> 16);
                    ai.y = 0; ai.z = 0; ai.w = 0;
                }
                const short8v afrag = *(short8v*)&ai;
                const f32x16 r0 = __builtin_amdgcn_mfma_f32_32x32x16_bf16(afrag, bfrag0, zero16, 0,0,0);
                const f32x16 r1 = __builtin_amdgcn_mfma_f32_32x32x16_bf16(afrag, bfrag1, zero16, 0,0,0);
                #pragma unroll
                for (int c = 0; c < 16; c += 4) {
                    m0 = fmaxf(m0, fmaxf(fmaxf(r0[c], r0[c+1]),
                                         fmaxf(r0[c+2], r0[c+3])));
                    m1 = fmaxf(m1, fmaxf(fmaxf(r1[c], r1[c+1]),
                                         fmaxf(r1[c+2], r1[c+3])));
                }
                w0 = nw0; w1 = nw1; w2 = nw2;
            }
            m0 = fmaxf(m0, __shfl_xor(m0, 32));
            m1 = fmaxf(m1, __shfl_xor(m1, 32));

            if (lane < 32) {
                const float x0 = pts[b*45 + n*3 + 0];
                const float x1 = pts[b*45 + n*3 + 1];
                const float x2 = pts[b*45 + n*3 + 2];
                {
                    const int o = lane;
                    const float4 qv = qTab4[o];
                    const float bias = fmaf(qv.x, x0, fmaf(qv.y, x1, fmaf(qv.z, x2, qv.w)));
                    h1s[n*64 + o] = fmaxf(m0 + bias, 0.f);
                }
                {
                    const int o = 32 + lane;
                    const float4 qv = qTab4[o];
                    const float bias = fmaf(qv.x, x0, fmaf(qv.y, x1, fmaf(qv.z, x2, qv.w)));
                    h1s[n*64 + o] = fmaxf(m1 + bias, 0.f);
                }
            }
        }
    }
    __syncthreads();

    // ---- conv2 phase -> h2 in LDS ----
    for (int idx = tid; idx < 2048; idx += 960) {
        const int o2 = idx & 127, n = idx >> 7;
        float val = 0.f;
        if (n < 15) {
            float acc = 0.f;
            #pragma unroll
            for (int cq = 0; cq < 16; ++cq) {
                const float4 h4 = *(const float4*)(&h1s[n*64 + cq*4]);
                const float4 w4 = w2q[cq*128 + o2];
                acc = fmaf(w4.x, h4.x, fmaf(w4.y, h4.y,
                      fmaf(w4.z, h4.z, fmaf(w4.w, h4.w, acc))));
            }
            val = fmaxf(acc + bias2[o2], 0.f);
        }
        const unsigned short hi = bf16r(val);
        const unsigned short lo = bf16r(val - bf2f(hi));
        h2hL[idx] = hi;
        h2lL[idx] = lo;
    }
    __syncthreads();

    // ---- conv3 + global-max phase -> g bf16 hi/lo (nt = wave, +15) ----
    {
        const int arow = lane & 15, agrp = lane >> 4;

        short8v ahi[4], alo[4];
        {
            const unsigned short* Ab = h2hL + arow*128 + agrp*8;
            const unsigned short* Al = h2lL + arow*128 + agrp*8;
            #pragma unroll
            for (int kt = 0; kt < 4; ++kt) {
                ahi[kt] = *(const short8v*)(Ab + kt*32);
                alo[kt] = *(const short8v*)(Al + kt*32);
            }
        }

        for (int nt = wave; nt < 64; nt += 15) {
            f32x4 a0 = {0.f, 0.f, 0.f, 0.f};
            f32x4 a1 = a0, a2 = a0;
            #pragma unroll
            for (int kt = 0; kt < 4; ++kt) {
                const size_t off = (((size_t)kt*64 + nt)*64 + lane) * 8;
                const short8v bh = *(const short8v*)(Bh + off);
                const short8v bl = *(const short8v*)(Bl + off);
                a0 = __builtin_amdgcn_mfma_f32_16x16x32_bf16(ahi[kt], bh, a0, 0, 0, 0);
                a1 = __builtin_amdgcn_mfma_f32_16x16x32_bf16(ahi[kt], bl, a1, 0, 0, 0);
                a2 = __builtin_amdgcn_mfma_f32_16x16x32_bf16(alo[kt], bh, a2, 0, 0, 0);
            }
            const float r0 = a0[0] + a1[0] + a2[0];
            const float r1 = a0[1] + a1[1] + a2[1];
            const float r2 = a0[2] + a1[2] + a2[2];
            const float r3 = a0[3] + a1[3] + a2[3];
            float m = fmaxf(fmaxf(r0, r1), r2);
            if (agrp != 3) m = fmaxf(m, r3);
            m = fmaxf(m, __shfl_xor(m, 16));
            m = fmaxf(m, __shfl_xor(m, 32));
            if (lane < 16) {
                const float val = m + bias3[nt*16 + lane];
                const unsigned short hi = bf16r(val);
                ghi[(size_t)b*1024 + nt*16 + lane] = hi;
                glo[(size_t)b*1024 + nt*16 + lane] = bf16r(val - bf2f(hi));
            }
        }
    }
}

// ---------------------------------------------------------------------------
// k_fc1m: fc1 via bf16x3 MFMA.  R31: 512 thr = 8 waves (was 4 = 1/SIMD),
// halving the per-wave serial K-chain (16 -> 8 kt) and doubling waves/SIMD.
// part grows to [8][32][33] = 33.8 KB.  (Same math; fp sum order only.)
// ---------------------------------------------------------------------------
__global__ __launch_bounds__(512) void k_fc1m(
    const unsigned short* __restrict__ gh,   // [256][1024]
    const unsigned short* __restrict__ gl,
    const unsigned short* __restrict__ B1h,  // [64][16][64][8]
    const unsigned short* __restrict__ B1l,
    const float* __restrict__ sf1, const float* __restrict__ cf1,
    unsigned short* __restrict__ f1h,        // [256][512]
    unsigned short* __restrict__ f1l)
{
    __shared__ float part[8][32][33];

    const int tid = threadIdx.x;
    const int bm = blockIdx.x * 32, bn = blockIdx.y * 32;
    const int wave = tid >> 6, lane = tid & 63;   // wave 0..7
    const int m = bm + (lane & 31);
    const int kgrp = (lane >> 5) << 3;

    f32x16 acc = {0.f,0.f,0.f,0.f,0.f,0.f,0.f,0.f,
                  0.f,0.f,0.f,0.f,0.f,0.f,0.f,0.f};

    for (int kt = wave*8; kt < wave*8 + 8; ++kt) {
        const int kb = kt*16 + kgrp;
        const short8v ah = *(const short8v*)(gh + (size_t)m*1024 + kb);
        const short8v al = *(const short8v*)(gl + (size_t)m*1024 + kb);
        const size_t boff = ((size_t)kt*1024 + blockIdx.y*64 + lane) * 8;
        const short8v bh = *(const short8v*)(B1h + boff);
        const short8v bl = *(const short8v*)(B1l + boff);
        acc = __builtin_amdgcn_mfma_f32_32x32x16_bf16(ah, bh, acc, 0,0,0);
        acc = __builtin_amdgcn_mfma_f32_32x32x16_bf16(ah, bl, acc, 0,0,0);
        acc = __builtin_amdgcn_mfma_f32_32x32x16_bf16(al, bh, acc, 0,0,0);
    }
    {
        const int n = lane & 31, mhl = (lane >> 5) << 2;
        #pragma unroll
        for (int reg = 0; reg < 16; ++reg) {
            const int mrow = (reg & 3) + 8*(reg >> 2) + mhl;
            part[wave][mrow][n] = acc[reg];
        }
    }
    __syncthreads();

    for (int i = tid; i < 1024; i += 512) {
        const int lm = i >> 5, ln = i & 31;
        float sum = part[0][lm][ln];
        #pragma unroll
        for (int w = 1; w < 8; ++w) sum += part[w][lm][ln];
        const int ch = bn + ln;
        const float val = fmaxf(fmaf(sf1[ch], sum, cf1[ch]), 0.f);
        const unsigned short hi = bf16r(val);
        f1h[(size_t)(bm + lm)*512 + ch] = hi;
        f1l[(size_t)(bm + lm)*512 + ch] = bf16r(val - bf2f(hi));
    }
}

// ---------------------------------------------------------------------------
// k_fc2m: fc2 via bf16x3 MFMA; 512 thr = 8 waves x 4 kt (was 4 x 8).
// Emits f2 fp32 (d_out) + bf16 hi/lo (ws).
// ---------------------------------------------------------------------------
__global__ __launch_bounds__(512) void k_fc2m(
    const unsigned short* __restrict__ f1h,  // [256][512]
    const unsigned short* __restrict__ f1l,
    const unsigned short* __restrict__ B2h,  // [32][8][64][8]
    const unsigned short* __restrict__ B2l,
    const float* __restrict__ sf2, const float* __restrict__ cf2,
    float* __restrict__ f2out,               // [256][256] fp32 (d_out tail)
    unsigned short* __restrict__ f2h,        // [256][256] bf16 hi
    unsigned short* __restrict__ f2l)        // [256][256] bf16 lo
{
    __shared__ float part[8][32][33];

    const int tid = threadIdx.x;
    const int bm = blockIdx.x * 32, bn = blockIdx.y * 32;
    const int wave = tid >> 6, lane = tid & 63;
    const int m = bm + (lane & 31);
    const int kgrp = (lane >> 5) << 3;

    f32x16 acc = {0.f,0.f,0.f,0.f,0.f,0.f,0.f,0.f,
                  0.f,0.f,0.f,0.f,0.f,0.f,0.f,0.f};

    for (int kt = wave*4; kt < wave*4 + 4; ++kt) {
        const int kb = kt*16 + kgrp;
        const short8v ah = *(const short8v*)(f1h + (size_t)m*512 + kb);
        const short8v al = *(const short8v*)(f1l + (size_t)m*512 + kb);
        const size_t boff = ((size_t)kt*512 + blockIdx.y*64 + lane) * 8;
        const short8v bh = *(const short8v*)(B2h + boff);
        const short8v bl = *(const short8v*)(B2l + boff);
        acc = __builtin_amdgcn_mfma_f32_32x32x16_bf16(ah, bh, acc, 0,0,0);
        acc = __builtin_amdgcn_mfma_f32_32x32x16_bf16(ah, bl, acc, 0,0,0);
        acc = __builtin_amdgcn_mfma_f32_32x32x16_bf16(al, bh, acc, 0,0,0);
    }
    {
        const int n = lane & 31, mhl = (lane >> 5) << 2;
        #pragma unroll
        for (int reg = 0; reg < 16; ++reg) {
            const int mrow = (reg & 3) + 8*(reg >> 2) + mhl;
            part[wave][mrow][n] = acc[reg];
        }
    }
    __syncthreads();

    for (int i = tid; i < 1024; i += 512) {
        const int lm = i >> 5, ln = i & 31;
        float sum = part[0][lm][ln];
        #pragma unroll
        for (int w = 1; w < 8; ++w) sum += part[w][lm][ln];
        const int ch = bn + ln;
        const float val = fmaxf(fmaf(sf2[ch], sum, cf2[ch]), 0.f);
        const size_t o = (size_t)(bm + lm)*256 + ch;
        f2out[o] = val;
        const unsigned short hi = bf16r(val);
        f2h[o] = hi;
        f2l[o] = bf16r(val - bf2f(hi));
    }
}

// ---------------------------------------------------------------------------
// k_fc3m: fc3 via bf16x3 MFMA; 512 thr = 8 waves x 2 kt (was 4 x 4).
// ---------------------------------------------------------------------------
__global__ __launch_bounds__(512) void k_fc3m(
    const unsigned short* __restrict__ f2h,  // [256][256]
    const unsigned short* __restrict__ f2l,
    const unsigned short* __restrict__ B3h,  // [16][25][64][8]
    const unsigned short* __restrict__ B3l,
    const float* __restrict__ bias,          // bf3 [800]
    float* __restrict__ C)                   // [256][800]
{
    __shared__ float part[8][32][33];

    const int tid = threadIdx.x;
    const int bm = blockIdx.x * 32;
    const int wave = tid >> 6, lane = tid & 63;
    const int m = bm + (lane & 31);
    const int kgrp = (lane >> 5) << 3;

    f32x16 acc = {0.f,0.f,0.f,0.f,0.f,0.f,0.f,0.f,
                  0.f,0.f,0.f,0.f,0.f,0.f,0.f,0.f};

    for (int kt = wave*2; kt < wave*2 + 2; ++kt) {
        const int kb = kt*16 + kgrp;
        const short8v ah = *(const short8v*)(f2h + (size_t)m*256 + kb);
        const short8v al = *(const short8v*)(f2l + (size_t)m*256 + kb);
        const size_t boff = (((size_t)kt*25 + blockIdx.y)*64 + lane) * 8;
        const short8v bh = *(const short8v*)(B3h + boff);
        const short8v bl = *(const short8v*)(B3l + boff);
        acc = __builtin_amdgcn_mfma_f32_32x32x16_bf16(ah, bh, acc, 0,0,0);
        acc = __builtin_amdgcn_mfma_f32_32x32x16_bf16(ah, bl, acc, 0,0,0);
        acc = __builtin_amdgcn_mfma_f32_32x32x16_bf16(al, bh, acc, 0,0,0);
    }
    {
        const int n = lane & 31, mhl = (lane >> 5) << 2;
        #pragma unroll
        for (int reg = 0; reg < 16; ++reg) {
            const int mrow = (reg & 3) + 8*(reg >> 2) + mhl;
            part[wave][mrow][n] = acc[reg];
        }
    }
    __syncthreads();

    for (int i = tid; i < 1024; i += 512) {
        const int lm = i >> 5, ln = i & 31;
        float sum = part[0][lm][ln];
        #pragma unroll
        for (int w = 1; w < 8; ++w) sum += part[w][lm][ln];
        const int ch = blockIdx.y * 32 + ln;             // < 800
        C[(size_t)(bm + lm)*800 + ch] = sum + bias[ch];
    }
}

// ---------------------------------------------------------------------------
extern "C" void kernel_launch(void* const* d_in, const int* in_sizes, int n_in,
                              void* d_out, int out_size, void* d_ws, size_t ws_size,
                              hipStream_t stream)
{
    const float* pts     = (const float*)d_in[0];
    const float* info    = (const float*)d_in[2];
    const float* w_info  = (const float*)d_in[3];
    const float* b_info  = (const float*)d_in[4];
    const float* g_info  = (const float*)d_in[5];
    const float* be_info = (const float*)d_in[6];
    const float* m_info  = (const float*)d_in[7];
    const float* v_info  = (const float*)d_in[8];
    const float* w2      = (const float*)d_in[9];
    const float* b2      = (const float*)d_in[10];
    const float* g2      = (const float*)d_in[11];
    const float* be2     = (const float*)d_in[12];
    const float* m2      = (const float*)d_in[13];
    const float* v2      = (const float*)d_in[14];
    const float* w3      = (const float*)d_in[15];
    const float* b3      = (const float*)d_in[16];
    const float* g3      = (const float*)d_in[17];
    const float* be3     = (const float*)d_in[18];
    const float* m3      = (const float*)d_in[19];
    const float* v3      = (const float*)d_in[20];
    const float* wf1     = (const float*)d_in[21];
    const float* bf1     = (const float*)d_in[22];
    const float* gf1     = (const float*)d_in[23];
    const float* bef1    = (const float*)d_in[24];
    const float* mf1     = (const float*)d_in[25];
    const float* vf1     = (const float*)d_in[26];
    const float* wf2     = (const float*)d_in[27];
    const float* bf2     = (const float*)d_in[28];
    const float* gf2     = (const float*)d_in[29];
    const float* bef2    = (const float*)d_in[30];
    const float* mf2     = (const float*)d_in[31];
    const float* vf2     = (const float*)d_in[32];
    const float* wf3     = (const float*)d_in[33];
    const float* bf3     = (const float*)d_in[34];

    float* ws = (float*)d_ws;
    // fc-MFMA region (float-slots = shorts/2):  (R23-validated layout)
    unsigned short* ghi   = (unsigned short*)(ws + 0);
    unsigned short* glo   = (unsigned short*)(ws + 131072);
    unsigned short* f2h   = (unsigned short*)(ws + 0);        // reuse dead ghi
    unsigned short* f2l   = (unsigned short*)(ws + 32768);
    unsigned short* f1h   = (unsigned short*)(ws + 262144);
    unsigned short* f1l   = (unsigned short*)(ws + 327680);
    unsigned short* B1h   = (unsigned short*)(ws + 393216);
    unsigned short* B1l   = (unsigned short*)(ws + 655360);
    unsigned short* B2h   = (unsigned short*)(ws + 917504);
    unsigned short* B2l   = (unsigned short*)(ws + 983040);
    unsigned short* B3h   = (unsigned short*)(ws + 1048576);
    unsigned short* B3l   = (unsigned short*)(ws + 1150976);
    // constants region (unchanged offsets):
    unsigned short* Bh    = (unsigned short*)(ws + 1277952);
    unsigned short* Bl    = (unsigned short*)(ws + 1343488);
    float*          bias3 = ws + 1409024;
    float4*         w2q   = (float4*)(ws + 1410048);
    float*          bias2 = ws + 1418240;
    float4*         qTab4 = (float4*)(ws + 1418624);
    float*          sf1   = ws + 1418880;
    float*          cf1   = ws + 1419392;
    float*          sf2   = ws + 1419904;
    float*          cf2   = ws + 1420160;
    unsigned short* Bedge = (unsigned short*)(ws + 1420416);

    float* ret = (float*)d_out;            // [256, 800]
    float* f2  = ret + 256 * 800;          // [256, 256]

    k_pre<<<486, 256, 0, stream>>>(
        w3, b3, g3, be3, m3, v3,
        w2, b2, g2, be2, m2, v2,
        w_info, b_info, g_info, be_info, m_info, v_info,
        bf1, gf1, bef1, mf1, vf1,
        bf2, gf2, bef2, mf2, vf2,
        wf1, wf2, wf3,
        Bh, Bl, bias3, w2q, bias2, Bedge, qTab4, sf1, cf1, sf2, cf2,
        B1h, B1l, B2h, B2l, B3h, B3l);

    k_edgeS3<<<256, 960, 0, stream>>>(pts, info, Bedge, qTab4,
                                      w2q, bias2, Bh, Bl, bias3, ghi, glo);

    k_fc1m<<<dim3(8, 16), 512, 0, stream>>>(ghi, glo, B1h, B1l,
                                            sf1, cf1, f1h, f1l);

    k_fc2m<<<dim3(8, 8), 512, 0, stream>>>(f1h, f1l, B2h, B2l,
                                           sf2, cf2, f2, f2h, f2l);

    k_fc3m<<<dim3(8, 25), 512, 0, stream>>>(f2h, f2l, B3h, B3l, bf3, ret);
}

// Round 32
// 53.619 us; speedup vs baseline: 2.0680x; 1.0153x over previous
//
#include <hip/hip_runtime.h>
#include <math.h>

#define EPS 1e-5f

typedef __attribute__((ext_vector_type(8))) short short8v;
typedef __attribute__((ext_vector_type(4))) float f32x4;
typedef __attribute__((ext_vector_type(16))) float f32x16;

// ---- bf16 split helpers (RNE) ----
__device__ __forceinline__ unsigned short bf16r(float x) {
    unsigned u = __float_as_uint(x);
    return (unsigned short)((u + 0x7FFFu + ((u >> 16) & 1u)) >> 16);
}
__device__ __forceinline__ float bf2f(unsigned short h) {
    return __uint_as_float(((unsigned)h) << 16);
}
__device__ __forceinline__ unsigned packhl(float x) {
    const unsigned short h = bf16r(x);
    const unsigned short l = bf16r(x - bf2f(h));
    return (unsigned)h | ((unsigned)l << 16);
}

// ---------------------------------------------------------------------------
// k_pre (486 blocks): conv3 Bpack (0..63), w2q/bias2 (64), Bedge/qTab/bias3/
// sf/cf (65), wf1->B1 (66..321), wf2->B2 (322..385), wf3->B3 (386..485).
// (R24-validated)
// ---------------------------------------------------------------------------
__global__ __launch_bounds__(256) void k_pre(
    const float* __restrict__ w3, const float* __restrict__ b3,
    const float* __restrict__ g3, const float* __restrict__ be3,
    const float* __restrict__ m3, const float* __restrict__ v3,
    const float* __restrict__ w2, const float* __restrict__ b2,
    const float* __restrict__ g2, const float* __restrict__ be2,
    const float* __restrict__ m2, const float* __restrict__ v2,
    const float* __restrict__ w_info, const float* __restrict__ b_info,
    const float* __restrict__ g_info, const float* __restrict__ be_info,
    const float* __restrict__ m_info, const float* __restrict__ v_info,
    const float* __restrict__ bf1, const float* __restrict__ gf1,
    const float* __restrict__ bef1, const float* __restrict__ mf1,
    const float* __restrict__ vf1,
    const float* __restrict__ bf2, const float* __restrict__ gf2,
    const float* __restrict__ bef2, const float* __restrict__ mf2,
    const float* __restrict__ vf2,
    const float* __restrict__ wf1, const float* __restrict__ wf2,
    const float* __restrict__ wf3,
    unsigned short* __restrict__ Bh, unsigned short* __restrict__ Bl,
    float* __restrict__ bias3,
    float4* __restrict__ w2q, float* __restrict__ bias2,
    unsigned short* __restrict__ Bedge,
    float4* __restrict__ qTab4,
    float* __restrict__ sf1, float* __restrict__ cf1,
    float* __restrict__ sf2, float* __restrict__ cf2,
    unsigned short* __restrict__ B1h, unsigned short* __restrict__ B1l,
    unsigned short* __restrict__ B2h, unsigned short* __restrict__ B2l,
    unsigned short* __restrict__ B3h, unsigned short* __restrict__ B3l)
{
    const int blk = blockIdx.x, tid = threadIdx.x;
    if (blk < 64) {
        const int t = blk * 256 + tid;
        const int kt = t >> 12;
        const int nt = (t >> 6) & 63;
        const int lane = t & 63;
        const int o  = nt * 16 + (lane & 15);
        const int kb = kt * 32 + ((lane >> 4) << 3);
        const float a3 = g3[o] * rsqrtf(v3[o] + EPS);
        #pragma unroll
        for (int j = 0; j < 8; ++j) {
            const float wv = a3 * w3[(size_t)o * 128 + kb + j];
            const unsigned short hi = bf16r(wv);
            Bh[(size_t)t * 8 + j] = hi;
            Bl[(size_t)t * 8 + j] = bf16r(wv - bf2f(hi));
        }
    } else if (blk == 64) {
        for (int idx = tid; idx < 2048; idx += 256) {
            const int o2 = idx & 127, cq = idx >> 7;
            const float a2 = g2[o2] * rsqrtf(v2[o2] + EPS);
            const float4 w = *(const float4*)(w2 + (size_t)o2 * 64 + cq * 4);
            w2q[cq * 128 + o2] = make_float4(a2 * w.x, a2 * w.y, a2 * w.z, a2 * w.w);
        }
        if (tid < 128) {
            const float a2 = g2[tid] * rsqrtf(v2[tid] + EPS);
            bias2[tid] = a2 * (b2[tid] - m2[tid]) + be2[tid];
        }
    } else if (blk == 65) {
        if (tid < 128) {
            const int nt = tid >> 6, lane = tid & 63;
            const int grp = lane >> 5;
            const int o = nt * 32 + (lane & 31);
            const float a = g_info[o] * rsqrtf(v_info[o] + EPS);
            const float c0 = a * w_info[o*6+0];
            const float c1 = a * w_info[o*6+1];
            const float c2 = a * w_info[o*6+2];
            const unsigned short ch0 = bf16r(c0), ch1 = bf16r(c1), ch2 = bf16r(c2);
            const unsigned short cl0 = bf16r(c0 - bf2f(ch0));
            const unsigned short cl1 = bf16r(c1 - bf2f(ch1));
            const unsigned short cl2 = bf16r(c2 - bf2f(ch2));
            unsigned short out[8] = {0,0,0,0,0,0,0,0};
            if (grp == 0) {
                out[0]=ch0; out[1]=ch1; out[2]=ch2;
                out[3]=cl0; out[4]=cl1; out[5]=cl2;
                out[6]=ch0; out[7]=ch1;
            } else {
                out[0]=ch2;
            }
            #pragma unroll
            for (int j = 0; j < 8; ++j)
                Bedge[(size_t)(nt*64 + lane)*8 + j] = out[j];
        }
        if (tid < 64) {
            const int o = tid;
            const float w0 = w_info[o*6+0], w1 = w_info[o*6+1], w2c = w_info[o*6+2];
            const float w3c = w_info[o*6+3], w4 = w_info[o*6+4], w5 = w_info[o*6+5];
            const float a = g_info[o] * rsqrtf(v_info[o] + EPS);
            qTab4[o] = make_float4(a*(w3c-w0), a*(w4-w1), a*(w5-w2c),
                                   a*(b_info[o]-m_info[o]) + be_info[o]);
        }
        for (int c = tid; c < 1024; c += 256) {
            const float a3 = g3[c] * rsqrtf(v3[c] + EPS);
            bias3[c] = a3 * (b3[c] - m3[c]) + be3[c];
        }
        for (int c = tid; c < 512; c += 256) {
            const float s = gf1[c] * rsqrtf(vf1[c] + EPS);
            sf1[c] = s;
            cf1[c] = s * (bf1[c] - mf1[c]) + bef1[c];
        }
        {
            const int c = tid;
            const float s = gf2[c] * rsqrtf(vf2[c] + EPS);
            sf2[c] = s;
            cf2[c] = s * (bf2[c] - mf2[c]) + bef2[c];
        }
    } else if (blk < 322) {
        const int idx = (blk - 66) * 256 + tid;
        const int lane = idx & 63;
        const int nt = (idx >> 6) & 15;
        const int kt = idx >> 10;
        const int n  = nt * 32 + (lane & 31);
        const int kb = kt * 16 + ((lane >> 5) << 3);
        #pragma unroll
        for (int j = 0; j < 8; ++j) {
            const float wv = wf1[(size_t)n * 1024 + kb + j];
            const unsigned short hi = bf16r(wv);
            B1h[(size_t)idx * 8 + j] = hi;
            B1l[(size_t)idx * 8 + j] = bf16r(wv - bf2f(hi));
        }
    } else if (blk < 386) {
        const int idx = (blk - 322) * 256 + tid;
        const int lane = idx & 63;
        const int nt = (idx >> 6) & 7;
        const int kt = idx >> 9;
        const int n  = nt * 32 + (lane & 31);
        const int kb = kt * 16 + ((lane >> 5) << 3);
        #pragma unroll
        for (int j = 0; j < 8; ++j) {
            const float wv = wf2[(size_t)n * 512 + kb + j];
            const unsigned short hi = bf16r(wv);
            B2h[(size_t)idx * 8 + j] = hi;
            B2l[(size_t)idx * 8 + j] = bf16r(wv - bf2f(hi));
        }
    } else {
        const int idx = (blk - 386) * 256 + tid;       // < 25600
        const int lane = idx & 63;
        const int g6 = idx >> 6;
        const int nt = g6 % 25;
        const int kt = g6 / 25;
        const int n  = nt * 32 + (lane & 31);          // < 800
        const int kb = kt * 16 + ((lane >> 5) << 3);
        #pragma unroll
        for (int j = 0; j < 8; ++j) {
            const float wv = wf3[(size_t)n * 256 + kb + j];
            const unsigned short hi = bf16r(wv);
            B3h[(size_t)idx * 8 + j] = hi;
            B3l[(size_t)idx * 8 + j] = bf16r(wv - bf2f(hi));
        }
    }
}

// ---------------------------------------------------------------------------
// k_edgeS3: fused edge-conv + max + conv2 + conv3 + global max.
// R32: depth-2 software pipeline of the conv3 B loads (issue nt+15's 8x16B
// before the MFMA cluster of nt; swap after epilogue).  Theory: conv3 is
// MLP-bound streaming 512 KB of Bh/Bl per CU with only ~8 loads in flight
// per wave and a vmcnt serialization per nt.  Same FP ops, same order.
// VGPR ~88+32 = ~120 < 128 cap at 4 waves/SIMD (960 thr = 4/4/4/3).
// Everything else is the R28-validated form.
// ---------------------------------------------------------------------------
__global__ __launch_bounds__(960) void k_edgeS3(
    const float* __restrict__ pts,
    const float* __restrict__ info,
    const unsigned short* __restrict__ Bedge,
    const float4* __restrict__ qTab4,
    const float4* __restrict__ w2q,
    const float* __restrict__ bias2,
    const unsigned short* __restrict__ Bh,
    const unsigned short* __restrict__ Bl,
    const float* __restrict__ bias3,
    unsigned short* __restrict__ ghi,     // [256][1024] bf16 hi
    unsigned short* __restrict__ glo)     // [256][1024] bf16 lo
{
    __shared__ unsigned dsb[23400];
    __shared__ float h1s[960];
    __shared__ unsigned short h2hL[2048];
    __shared__ unsigned short h2lL[2048];

    const int tid = threadIdx.x;
    const int b = blockIdx.x;

    {
        const float4* src = (const float4*)(info + (size_t)b * 23400);
        uint4* dst = (uint4*)dsb;
        for (int i = tid; i < 5850; i += 960) {
            const float4 v = src[i];
            uint4 pv;
            pv.x = packhl(v.x); pv.y = packhl(v.y);
            pv.z = packhl(v.z); pv.w = packhl(v.w);
            dst[i] = pv;
        }
    }
    __syncthreads();

    const int wave = tid >> 6, lane = tid & 63;   // wave: 0..14
    const int la = lane & 31;
    const bool hiHalf = lane >= 32;

    {   // ---- edge-conv phase (depth-2 LDS prefetch; one n per wave) ----
        short8v bfrag0 = *(const short8v*)(Bedge + (size_t)(0*64 + lane)*8);
        short8v bfrag1 = *(const short8v*)(Bedge + (size_t)(1*64 + lane)*8);

        const f32x16 zero16 = {0.f,0.f,0.f,0.f,0.f,0.f,0.f,0.f,
                               0.f,0.f,0.f,0.f,0.f,0.f,0.f,0.f};

        {
            const int n = wave;
            float m0 = -INFINITY, m1 = -INFINITY;
            const unsigned* pb = dsb + n*3;

            unsigned w0 = 0, w1 = 0, w2 = 0;
            {
                const unsigned* p = pb + la*45;
                if (!hiHalf) { w0 = p[0]; w1 = p[1]; }
                w2 = p[2];
            }

            #pragma unroll 1
            for (int mt = 0; mt < 17; ++mt) {
                unsigned nw0 = 0, nw1 = 0, nw2 = 0;
                if (mt < 16) {
                    int nrow = (mt+1)*32 + la;
                    nrow = nrow > 519 ? 519 : nrow;
                    const unsigned* p = pb + nrow*45;
                    if (!hiHalf) { nw0 = p[0]; nw1 = p[1]; }
                    nw2 = p[2];
                }
                int4 ai;
                if (!hiHalf) {
                    ai.x = (int)((w0 & 0xFFFFu) | (w1 << 16));
                    ai.y = (int)((w2 & 0xFFFFu) | (w0 << 16));
                    ai.z = (int)((w1 & 0xFFFFu) | (w2 << 16));
                    ai.w = (int)((w0 >> 16) | (w1 & 0xFFFF0000u));
                } else {
                    ai.x = (int)(w2 >> 16);
                    ai.y = 0; ai.z = 0; ai.w = 0;
                }
                const short8v afrag = *(short8v*)&ai;
                const f32x16 r0 = __builtin_amdgcn_mfma_f32_32x32x16_bf16(afrag, bfrag0, zero16, 0,0,0);
                const f32x16 r1 = __builtin_amdgcn_mfma_f32_32x32x16_bf16(afrag, bfrag1, zero16, 0,0,0);
                #pragma unroll
                for (int c = 0; c < 16; c += 4) {
                    m0 = fmaxf(m0, fmaxf(fmaxf(r0[c], r0[c+1]),
                                         fmaxf(r0[c+2], r0[c+3])));
                    m1 = fmaxf(m1, fmaxf(fmaxf(r1[c], r1[c+1]),
                                         fmaxf(r1[c+2], r1[c+3])));
                }
                w0 = nw0; w1 = nw1; w2 = nw2;
            }
            m0 = fmaxf(m0, __shfl_xor(m0, 32));
            m1 = fmaxf(m1, __shfl_xor(m1, 32));

            if (lane < 32) {
                const float x0 = pts[b*45 + n*3 + 0];
                const float x1 = pts[b*45 + n*3 + 1];
                const float x2 = pts[b*45 + n*3 + 2];
                {
                    const int o = lane;
                    const float4 qv = qTab4[o];
                    const float bias = fmaf(qv.x, x0, fmaf(qv.y, x1, fmaf(qv.z, x2, qv.w)));
                    h1s[n*64 + o] = fmaxf(m0 + bias, 0.f);
                }
                {
                    const int o = 32 + lane;
                    const float4 qv = qTab4[o];
                    const float bias = fmaf(qv.x, x0, fmaf(qv.y, x1, fmaf(qv.z, x2, qv.w)));
                    h1s[n*64 + o] = fmaxf(m1 + bias, 0.f);
                }
            }
        }
    }
    __syncthreads();

    // ---- conv2 phase -> h2 in LDS ----
    for (int idx = tid; idx < 2048; idx += 960) {
        const int o2 = idx & 127, n = idx >> 7;
        float val = 0.f;
        if (n < 15) {
            float acc = 0.f;
            #pragma unroll
            for (int cq = 0; cq < 16; ++cq) {
                const float4 h4 = *(const float4*)(&h1s[n*64 + cq*4]);
                const float4 w4 = w2q[cq*128 + o2];
                acc = fmaf(w4.x, h4.x, fmaf(w4.y, h4.y,
                      fmaf(w4.z, h4.z, fmaf(w4.w, h4.w, acc))));
            }
            val = fmaxf(acc + bias2[o2], 0.f);
        }
        const unsigned short hi = bf16r(val);
        const unsigned short lo = bf16r(val - bf2f(hi));
        h2hL[idx] = hi;
        h2lL[idx] = lo;
    }
    __syncthreads();

    // ---- conv3 + global-max phase (depth-2 B prefetch over nt) ----
    {
        const int arow = lane & 15, agrp = lane >> 4;

        short8v ahi[4], alo[4];
        {
            const unsigned short* Ab = h2hL + arow*128 + agrp*8;
            const unsigned short* Al = h2lL + arow*128 + agrp*8;
            #pragma unroll
            for (int kt = 0; kt < 4; ++kt) {
                ahi[kt] = *(const short8v*)(Ab + kt*32);
                alo[kt] = *(const short8v*)(Al + kt*32);
            }
        }

        // prologue: load B for the first nt of this wave
        short8v cbh[4], cbl[4];
        {
            const int nt0 = wave;
            #pragma unroll
            for (int kt = 0; kt < 4; ++kt) {
                const size_t off = (((size_t)kt*64 + nt0)*64 + lane) * 8;
                cbh[kt] = *(const short8v*)(Bh + off);
                cbl[kt] = *(const short8v*)(Bl + off);
            }
        }

        #pragma unroll 1
        for (int nt = wave; nt < 64; nt += 15) {
            // issue next-nt B loads first; they drain behind the MFMA cluster
            const int ntn = (nt + 15 < 64) ? nt + 15 : nt;   // clamp: dummy on last
            short8v nbh[4], nbl[4];
            #pragma unroll
            for (int kt = 0; kt < 4; ++kt) {
                const size_t off = (((size_t)kt*64 + ntn)*64 + lane) * 8;
                nbh[kt] = *(const short8v*)(Bh + off);
                nbl[kt] = *(const short8v*)(Bl + off);
            }

            f32x4 a0 = {0.f, 0.f, 0.f, 0.f};
            f32x4 a1 = a0, a2 = a0;
            #pragma unroll
            for (int kt = 0; kt < 4; ++kt) {
                a0 = __builtin_amdgcn_mfma_f32_16x16x32_bf16(ahi[kt], cbh[kt], a0, 0, 0, 0);
                a1 = __builtin_amdgcn_mfma_f32_16x16x32_bf16(ahi[kt], cbl[kt], a1, 0, 0, 0);
                a2 = __builtin_amdgcn_mfma_f32_16x16x32_bf16(alo[kt], cbh[kt], a2, 0, 0, 0);
            }
            const float r0 = a0[0] + a1[0] + a2[0];
            const float r1 = a0[1] + a1[1] + a2[1];
            const float r2 = a0[2] + a1[2] + a2[2];
            const float r3 = a0[3] + a1[3] + a2[3];
            float m = fmaxf(fmaxf(r0, r1), r2);
            if (agrp != 3) m = fmaxf(m, r3);
            m = fmaxf(m, __shfl_xor(m, 16));
            m = fmaxf(m, __shfl_xor(m, 32));
            if (lane < 16) {
                const float val = m + bias3[nt*16 + lane];
                const unsigned short hi = bf16r(val);
                ghi[(size_t)b*1024 + nt*16 + lane] = hi;
                glo[(size_t)b*1024 + nt*16 + lane] = bf16r(val - bf2f(hi));
            }
            #pragma unroll
            for (int kt = 0; kt < 4; ++kt) { cbh[kt] = nbh[kt]; cbl[kt] = nbl[kt]; }
        }
    }
}

// ---------------------------------------------------------------------------
// k_fc1m: fc1 via bf16x3 MFMA.  (R31-validated: 512 thr = 8 waves x 8 kt)
// ---------------------------------------------------------------------------
__global__ __launch_bounds__(512) void k_fc1m(
    const unsigned short* __restrict__ gh,   // [256][1024]
    const unsigned short* __restrict__ gl,
    const unsigned short* __restrict__ B1h,  // [64][16][64][8]
    const unsigned short* __restrict__ B1l,
    const float* __restrict__ sf1, const float* __restrict__ cf1,
    unsigned short* __restrict__ f1h,        // [256][512]
    unsigned short* __restrict__ f1l)
{
    __shared__ float part[8][32][33];

    const int tid = threadIdx.x;
    const int bm = blockIdx.x * 32, bn = blockIdx.y * 32;
    const int wave = tid >> 6, lane = tid & 63;   // wave 0..7
    const int m = bm + (lane & 31);
    const int kgrp = (lane >> 5) << 3;

    f32x16 acc = {0.f,0.f,0.f,0.f,0.f,0.f,0.f,0.f,
                  0.f,0.f,0.f,0.f,0.f,0.f,0.f,0.f};

    for (int kt = wave*8; kt < wave*8 + 8; ++kt) {
        const int kb = kt*16 + kgrp;
        const short8v ah = *(const short8v*)(gh + (size_t)m*1024 + kb);
        const short8v al = *(const short8v*)(gl + (size_t)m*1024 + kb);
        const size_t boff = ((size_t)kt*1024 + blockIdx.y*64 + lane) * 8;
        const short8v bh = *(const short8v*)(B1h + boff);
        const short8v bl = *(const short8v*)(B1l + boff);
        acc = __builtin_amdgcn_mfma_f32_32x32x16_bf16(ah, bh, acc, 0,0,0);
        acc = __builtin_amdgcn_mfma_f32_32x32x16_bf16(ah, bl, acc, 0,0,0);
        acc = __builtin_amdgcn_mfma_f32_32x32x16_bf16(al, bh, acc, 0,0,0);
    }
    {
        const int n = lane & 31, mhl = (lane >> 5) << 2;
        #pragma unroll
        for (int reg = 0; reg < 16; ++reg) {
            const int mrow = (reg & 3) + 8*(reg >> 2) + mhl;
            part[wave][mrow][n] = acc[reg];
        }
    }
    __syncthreads();

    for (int i = tid; i < 1024; i += 512) {
        const int lm = i >> 5, ln = i & 31;
        float sum = part[0][lm][ln];
        #pragma unroll
        for (int w = 1; w < 8; ++w) sum += part[w][lm][ln];
        const int ch = bn + ln;
        const float val = fmaxf(fmaf(sf1[ch], sum, cf1[ch]), 0.f);
        const unsigned short hi = bf16r(val);
        f1h[(size_t)(bm + lm)*512 + ch] = hi;
        f1l[(size_t)(bm + lm)*512 + ch] = bf16r(val - bf2f(hi));
    }
}

// ---------------------------------------------------------------------------
// k_fc2m: fc2 via bf16x3 MFMA; 512 thr = 8 waves x 4 kt.  (R31-validated)
// ---------------------------------------------------------------------------
__global__ __launch_bounds__(512) void k_fc2m(
    const unsigned short* __restrict__ f1h,  // [256][512]
    const unsigned short* __restrict__ f1l,
    const unsigned short* __restrict__ B2h,  // [32][8][64][8]
    const unsigned short* __restrict__ B2l,
    const float* __restrict__ sf2, const float* __restrict__ cf2,
    float* __restrict__ f2out,               // [256][256] fp32 (d_out tail)
    unsigned short* __restrict__ f2h,        // [256][256] bf16 hi
    unsigned short* __restrict__ f2l)        // [256][256] bf16 lo
{
    __shared__ float part[8][32][33];

    const int tid = threadIdx.x;
    const int bm = blockIdx.x * 32, bn = blockIdx.y * 32;
    const int wave = tid >> 6, lane = tid & 63;
    const int m = bm + (lane & 31);
    const int kgrp = (lane >> 5) << 3;

    f32x16 acc = {0.f,0.f,0.f,0.f,0.f,0.f,0.f,0.f,
                  0.f,0.f,0.f,0.f,0.f,0.f,0.f,0.f};

    for (int kt = wave*4; kt < wave*4 + 4; ++kt) {
        const int kb = kt*16 + kgrp;
        const short8v ah = *(const short8v*)(f1h + (size_t)m*512 + kb);
        const short8v al = *(const short8v*)(f1l + (size_t)m*512 + kb);
        const size_t boff = ((size_t)kt*512 + blockIdx.y*64 + lane) * 8;
        const short8v bh = *(const short8v*)(B2h + boff);
        const short8v bl = *(const short8v*)(B2l + boff);
        acc = __builtin_amdgcn_mfma_f32_32x32x16_bf16(ah, bh, acc, 0,0,0);
        acc = __builtin_amdgcn_mfma_f32_32x32x16_bf16(ah, bl, acc, 0,0,0);
        acc = __builtin_amdgcn_mfma_f32_32x32x16_bf16(al, bh, acc, 0,0,0);
    }
    {
        const int n = lane & 31, mhl = (lane >> 5) << 2;
        #pragma unroll
        for (int reg = 0; reg < 16; ++reg) {
            const int mrow = (reg & 3) + 8*(reg >> 2) + mhl;
            part[wave][mrow][n] = acc[reg];
        }
    }
    __syncthreads();

    for (int i = tid; i < 1024; i += 512) {
        const int lm = i >> 5, ln = i & 31;
        float sum = part[0][lm][ln];
        #pragma unroll
        for (int w = 1; w < 8; ++w) sum += part[w][lm][ln];
        const int ch = bn + ln;
        const float val = fmaxf(fmaf(sf2[ch], sum, cf2[ch]), 0.f);
        const size_t o = (size_t)(bm + lm)*256 + ch;
        f2out[o] = val;
        const unsigned short hi = bf16r(val);
        f2h[o] = hi;
        f2l[o] = bf16r(val - bf2f(hi));
    }
}

// ---------------------------------------------------------------------------
// k_fc3m: fc3 via bf16x3 MFMA; 512 thr = 8 waves x 2 kt.  (R31-validated)
// ---------------------------------------------------------------------------
__global__ __launch_bounds__(512) void k_fc3m(
    const unsigned short* __restrict__ f2h,  // [256][256]
    const unsigned short* __restrict__ f2l,
    const unsigned short* __restrict__ B3h,  // [16][25][64][8]
    const unsigned short* __restrict__ B3l,
    const float* __restrict__ bias,          // bf3 [800]
    float* __restrict__ C)                   // [256][800]
{
    __shared__ float part[8][32][33];

    const int tid = threadIdx.x;
    const int bm = blockIdx.x * 32;
    const int wave = tid >> 6, lane = tid & 63;
    const int m = bm + (lane & 31);
    const int kgrp = (lane >> 5) << 3;

    f32x16 acc = {0.f,0.f,0.f,0.f,0.f,0.f,0.f,0.f,
                  0.f,0.f,0.f,0.f,0.f,0.f,0.f,0.f};

    for (int kt = wave*2; kt < wave*2 + 2; ++kt) {
        const int kb = kt*16 + kgrp;
        const short8v ah = *(const short8v*)(f2h + (size_t)m*256 + kb);
        const short8v al = *(const short8v*)(f2l + (size_t)m*256 + kb);
        const size_t boff = (((size_t)kt*25 + blockIdx.y)*64 + lane) * 8;
        const short8v bh = *(const short8v*)(B3h + boff);
        const short8v bl = *(const short8v*)(B3l + boff);
        acc = __builtin_amdgcn_mfma_f32_32x32x16_bf16(ah, bh, acc, 0,0,0);
        acc = __builtin_amdgcn_mfma_f32_32x32x16_bf16(ah, bl, acc, 0,0,0);
        acc = __builtin_amdgcn_mfma_f32_32x32x16_bf16(al, bh, acc, 0,0,0);
    }
    {
        const int n = lane & 31, mhl = (lane >> 5) << 2;
        #pragma unroll
        for (int reg = 0; reg < 16; ++reg) {
            const int mrow = (reg & 3) + 8*(reg >> 2) + mhl;
            part[wave][mrow][n] = acc[reg];
        }
    }
    __syncthreads();

    for (int i = tid; i < 1024; i += 512) {
        const int lm = i >> 5, ln = i & 31;
        float sum = part[0][lm][ln];
        #pragma unroll
        for (int w = 1; w < 8; ++w) sum += part[w][lm][ln];
        const int ch = blockIdx.y * 32 + ln;             // < 800
        C[(size_t)(bm + lm)*800 + ch] = sum + bias[ch];
    }
}

// ---------------------------------------------------------------------------
extern "C" void kernel_launch(void* const* d_in, const int* in_sizes, int n_in,
                              void* d_out, int out_size, void* d_ws, size_t ws_size,
                              hipStream_t stream)
{
    const float* pts     = (const float*)d_in[0];
    const float* info    = (const float*)d_in[2];
    const float* w_info  = (const float*)d_in[3];
    const float* b_info  = (const float*)d_in[4];
    const float* g_info  = (const float*)d_in[5];
    const float* be_info = (const float*)d_in[6];
    const float* m_info  = (const float*)d_in[7];
    const float* v_info  = (const float*)d_in[8];
    const float* w2      = (const float*)d_in[9];
    const float* b2      = (const float*)d_in[10];
    const float* g2      = (const float*)d_in[11];
    const float* be2     = (const float*)d_in[12];
    const float* m2      = (const float*)d_in[13];
    const float* v2      = (const float*)d_in[14];
    const float* w3      = (const float*)d_in[15];
    const float* b3      = (const float*)d_in[16];
    const float* g3      = (const float*)d_in[17];
    const float* be3     = (const float*)d_in[18];
    const float* m3      = (const float*)d_in[19];
    const float* v3      = (const float*)d_in[20];
    const float* wf1     = (const float*)d_in[21];
    const float* bf1     = (const float*)d_in[22];
    const float* gf1     = (const float*)d_in[23];
    const float* bef1    = (const float*)d_in[24];
    const float* mf1     = (const float*)d_in[25];
    const float* vf1     = (const float*)d_in[26];
    const float* wf2     = (const float*)d_in[27];
    const float* bf2     = (const float*)d_in[28];
    const float* gf2     = (const float*)d_in[29];
    const float* bef2    = (const float*)d_in[30];
    const float* mf2     = (const float*)d_in[31];
    const float* vf2     = (const float*)d_in[32];
    const float* wf3     = (const float*)d_in[33];
    const float* bf3     = (const float*)d_in[34];

    float* ws = (float*)d_ws;
    // fc-MFMA region (float-slots = shorts/2):  (R23-validated layout)
    unsigned short* ghi   = (unsigned short*)(ws + 0);
    unsigned short* glo   = (unsigned short*)(ws + 131072);
    unsigned short* f2h   = (unsigned short*)(ws + 0);        // reuse dead ghi
    unsigned short* f2l   = (unsigned short*)(ws + 32768);
    unsigned short* f1h   = (unsigned short*)(ws + 262144);
    unsigned short* f1l   = (unsigned short*)(ws + 327680);
    unsigned short* B1h   = (unsigned short*)(ws + 393216);
    unsigned short* B1l   = (unsigned short*)(ws + 655360);
    unsigned short* B2h   = (unsigned short*)(ws + 917504);
    unsigned short* B2l   = (unsigned short*)(ws + 983040);
    unsigned short* B3h   = (unsigned short*)(ws + 1048576);
    unsigned short* B3l   = (unsigned short*)(ws + 1150976);
    // constants region (unchanged offsets):
    unsigned short* Bh    = (unsigned short*)(ws + 1277952);
    unsigned short* Bl    = (unsigned short*)(ws + 1343488);
    float*          bias3 = ws + 1409024;
    float4*         w2q   = (float4*)(ws + 1410048);
    float*          bias2 = ws + 1418240;
    float4*         qTab4 = (float4*)(ws + 1418624);
    float*          sf1   = ws + 1418880;
    float*          cf1   = ws + 1419392;
    float*          sf2   = ws + 1419904;
    float*          cf2   = ws + 1420160;
    unsigned short* Bedge = (unsigned short*)(ws + 1420416);

    float* ret = (float*)d_out;            // [256, 800]
    float* f2  = ret + 256 * 800;          // [256, 256]

    k_pre<<<486, 256, 0, stream>>>(
        w3, b3, g3, be3, m3, v3,
        w2, b2, g2, be2, m2, v2,
        w_info, b_info, g_info, be_info, m_info, v_info,
        bf1, gf1, bef1, mf1, vf1,
        bf2, gf2, bef2, mf2, vf2,
        wf1, wf2, wf3,
        Bh, Bl, bias3, w2q, bias2, Bedge, qTab4, sf1, cf1, sf2, cf2,
        B1h, B1l, B2h, B2l, B3h, B3l);

    k_edgeS3<<<256, 960, 0, stream>>>(pts, info, Bedge, qTab4,
                                      w2q, bias2, Bh, Bl, bias3, ghi, glo);

    k_fc1m<<<dim3(8, 16), 512, 0, stream>>>(ghi, glo, B1h, B1l,
                                            sf1, cf1, f1h, f1l);

    k_fc2m<<<dim3(8, 8), 512, 0, stream>>>(f1h, f1l, B2h, B2l,
                                           sf2, cf2, f2, f2h, f2l);

    k_fc3m<<<dim3(8, 25), 512, 0, stream>>>(f2h, f2l, B3h, B3l, bf3, ret);
}